// Round 8
// baseline (871.985 us; speedup 1.0000x reference)
//
#include <hip/hip_runtime.h>
#include <math.h>

#define EPSF 1e-8f
#define LN_EPS 1e-5f
#define BL_MARGIN 0.002f   // > bound on fp16 unit-vector cosine-sim error (~1.5e-3)

#define BKT_SH 8           // 256 cols per bucket
#define NBKT 512           // needs N <= 131072
#define CHUNK 2048         // edges per binfill block
// Per-bucket edges ~ Binomial: mean = 256 cols x (E/N=16) = 4096, sigma ~ 64.
// R5 CRASH POST-MORTEM: BCAP must exceed mean+16sigma (3840 < 4096 faulted).
#define BCAP 5120

typedef unsigned int  u32;
typedef unsigned short u16;
typedef _Float16 h2_t __attribute__((ext_vector_type(2)));
typedef _Float16 half8_t __attribute__((ext_vector_type(8)));
typedef float f32x4_t __attribute__((ext_vector_type(4)));

static __device__ inline u32 pack_h2(float a, float b) {
    h2_t h; h.x = (_Float16)a; h.y = (_Float16)b;
    return __builtin_bit_cast(u32, h);
}
static __device__ inline float h2lo(u32 u) {
    return (float)__builtin_bit_cast(h2_t, u).x;
}
static __device__ inline float h2hi(u32 u) {
    return (float)__builtin_bit_cast(h2_t, u).y;
}

// D = A(16x32 f16) * B(32x16 f16) + C, fp32 accumulate.
static __device__ inline f32x4_t mfma16(uint4 a, uint4 b, f32x4_t c) {
    return __builtin_amdgcn_mfma_f32_16x16x32_f16(
        __builtin_bit_cast(half8_t, a), __builtin_bit_cast(half8_t, b), c, 0, 0, 0);
}
static __device__ inline float sel4(f32x4_t a, int m) {
    return m == 0 ? a[0] : m == 1 ? a[1] : m == 2 ? a[2] : a[3];
}

// ---------------- layer-1 prep: norms + UNIT-vector fp16 cast (+deg1 zero) -----
__global__ __launch_bounds__(256) void cast_norm_k(const float* __restrict__ feat,
    u32* __restrict__ fhf, float* __restrict__ nrm, float* __restrict__ deg1, int n) {
    int wid  = (blockIdx.x * 256 + threadIdx.x) >> 6;
    int lane = threadIdx.x & 63;
    if (wid >= n) return;
    float2 v = *(const float2*)(feat + (size_t)wid * 128 + lane * 2);
    float s = v.x * v.x + v.y * v.y;
    #pragma unroll
    for (int off = 32; off; off >>= 1) s += __shfl_xor(s, off, 64);
    float nv = fmaxf(sqrtf(s), EPSF);
    float inv = 1.0f / nv;
    fhf[(size_t)wid * 64 + lane] = pack_h2(v.x * inv, v.y * inv);
    if (lane == 0) { nrm[wid] = nv; deg1[wid] = 0.0f; }
}

// ---------------- one-time CSR build: fixed-capacity bucketed sort ----------------
__global__ __launch_bounds__(256) void binfill_k(const int* __restrict__ row,
    const int* __restrict__ col, int* __restrict__ bcur,
    int2* __restrict__ ebuf, int ecnt) {
    __shared__ int lc[NBKT], ls[NBKT], cur[NBKT], gbase[NBKT];
    __shared__ int2 pairs[CHUNK];
    __shared__ int dstv[CHUNK];
    int t = threadIdx.x;
    int e0 = blockIdx.x * CHUNK;
    int m = min(CHUNK, ecnt - e0);
    lc[t] = 0; lc[t + 256] = 0; cur[t] = 0; cur[t + 256] = 0;
    __syncthreads();
    int myc[CHUNK / 256], myr[CHUNK / 256];
    #pragma unroll
    for (int i = 0; i < CHUNK / 256; ++i) {
        int idx = t + i * 256;
        if (idx < m) {
            myc[i] = col[e0 + idx];
            myr[i] = row[e0 + idx];
            atomicAdd(&lc[myc[i] >> BKT_SH], 1);
        }
    }
    __syncthreads();
    int v0 = lc[t], v1 = lc[t + 256];
    ls[t] = v0; ls[t + 256] = v1; __syncthreads();
    for (int off = 1; off < 256; off <<= 1) {
        int a0 = (t >= off) ? ls[t - off] : 0;
        int a1 = (t >= off) ? ls[256 + t - off] : 0;
        __syncthreads();
        ls[t] += a0; ls[t + 256] += a1;
        __syncthreads();
    }
    int h0 = ls[255];
    int e0x = ls[t] - v0;
    int e1x = ls[t + 256] - v1 + h0;
    __syncthreads();
    ls[t] = e0x; ls[t + 256] = e1x;
    if (v0) gbase[t] = atomicAdd(&bcur[t], v0);
    if (v1) gbase[t + 256] = atomicAdd(&bcur[t + 256], v1);
    __syncthreads();
    #pragma unroll
    for (int i = 0; i < CHUNK / 256; ++i) {
        int idx = t + i * 256;
        if (idx < m) {
            int b = myc[i] >> BKT_SH;
            int s = ls[b] + atomicAdd(&cur[b], 1);
            pairs[s] = make_int2(myc[i], myr[i]);
            int pos = gbase[b] + (s - ls[b]);
            dstv[s]  = (pos < BCAP) ? (b * BCAP + pos) : -1;
        }
    }
    __syncthreads();
    for (int s = t; s < m; s += 256) {
        int d = dstv[s];
        if (d >= 0) ebuf[d] = pairs[s];
    }
}

__global__ __launch_bounds__(256) void bucket_csr_k(const int2* __restrict__ ebuf,
    const int* __restrict__ bcur, int* __restrict__ startAll,
    int* __restrict__ cntAll, int* __restrict__ rowAll, int* __restrict__ colAll,
    int n) {
    __shared__ int sc[NBKT];
    __shared__ int cnt[256], lst[256], cur[256];
    __shared__ int rowbuf[BCAP];
    int b = blockIdx.x, t = threadIdx.x;
    int c0 = b << BKT_SH;
    int s0v = min(bcur[t], BCAP), s1v = min(bcur[t + 256], BCAP);
    sc[t] = s0v; sc[t + 256] = s1v; __syncthreads();
    for (int off = 1; off < 256; off <<= 1) {
        int a0 = (t >= off) ? sc[t - off] : 0;
        int a1 = (t >= off) ? sc[256 + t - off] : 0;
        __syncthreads();
        sc[t] += a0; sc[t + 256] += a1;
        __syncthreads();
    }
    int m  = min(bcur[b], BCAP);
    int g0 = ((b >= 256) ? sc[255] : 0) + sc[b] - m;
    size_t ebase = (size_t)b * BCAP;
    cnt[t] = 0; cur[t] = 0;
    __syncthreads();
    for (int i = t; i < m; i += 256)
        atomicAdd(&cnt[ebuf[ebase + i].x - c0], 1);
    __syncthreads();
    int v = cnt[t];
    lst[t] = v; __syncthreads();
    for (int off = 1; off < 256; off <<= 1) {
        int a = (t >= off) ? lst[t - off] : 0;
        __syncthreads();
        lst[t] += a;
        __syncthreads();
    }
    int ex = lst[t] - v;
    __syncthreads();
    lst[t] = ex;
    __syncthreads();
    int c = c0 + t;
    if (c < n) { startAll[c] = g0 + lst[t]; cntAll[c] = cnt[t]; }
    for (int i = t; i < m; i += 256) {
        int2 p = ebuf[ebase + i];
        int ci = p.x - c0;
        int pos = lst[ci] + atomicAdd(&cur[ci], 1);
        rowbuf[pos] = p.y;
    }
    __syncthreads();
    for (int i = t; i < m; i += 256)
        rowAll[g0 + i] = rowbuf[i];
    __syncthreads();
    {
        int base = lst[t], cn = cnt[t], cc = c0 + t;
        for (int k2 = 0; k2 < cn; ++k2) rowbuf[base + k2] = cc;
    }
    __syncthreads();
    for (int i = t; i < m; i += 256)
        colAll[g0 + i] = rowbuf[i];
}

// ---------------- edge-dot body (flat edge-parallel MFMA dots) ----------------
// R1-R3: pinned at ~91us; per-CU outstanding-miss x latency floor for the
// 1.6M x 256B random gather. R8: its idle VALU/occupancy slack now hosts the
// fused GEMM blocks (see fused1_k/fused2_k).
static __device__ inline void edge_dot_body(int ewk, const u32* __restrict__ fhf,
    const float* __restrict__ feat32, const int* __restrict__ rowAll,
    const int* __restrict__ colAll, const float* __restrict__ nrm,
    float* __restrict__ sims, float* __restrict__ deg1, int ecnt) {
    int lane = threadIdx.x & 63;
    int e0 = (ewk * 4 + (int)(threadIdx.x >> 6)) * 32;
    if (e0 >= ecnt) return;
    int lr = lane & 15, kq = lane >> 4;
    bool diag = (kq == (lr >> 2));
    int m3 = lane & 3;
    int em1 = ecnt - 1;

    int e1 = e0 + lr, e2 = e0 + 16 + lr;
    int e1c = min(e1, em1), e2c = min(e2, em1);
    int r1 = rowAll[e1c], c1 = colAll[e1c];
    int r2 = rowAll[e2c], c2 = colAll[e2c];
    const u32* pa1 = fhf + (size_t)c1 * 64 + kq * 4;
    const u32* pb1 = fhf + (size_t)r1 * 64 + kq * 4;
    const u32* pa2 = fhf + (size_t)c2 * 64 + kq * 4;
    const u32* pb2 = fhf + (size_t)r2 * 64 + kq * 4;
    uint4 a10 = *(const uint4*)(pa1);
    uint4 a11 = *(const uint4*)(pa1 + 16);
    uint4 a12 = *(const uint4*)(pa1 + 32);
    uint4 a13 = *(const uint4*)(pa1 + 48);
    uint4 b10 = *(const uint4*)(pb1);
    uint4 b11 = *(const uint4*)(pb1 + 16);
    uint4 b12 = *(const uint4*)(pb1 + 32);
    uint4 b13 = *(const uint4*)(pb1 + 48);
    uint4 a20 = *(const uint4*)(pa2);
    uint4 a21 = *(const uint4*)(pa2 + 16);
    uint4 a22 = *(const uint4*)(pa2 + 32);
    uint4 a23 = *(const uint4*)(pa2 + 48);
    uint4 b20 = *(const uint4*)(pb2);
    uint4 b21 = *(const uint4*)(pb2 + 16);
    uint4 b22 = *(const uint4*)(pb2 + 32);
    uint4 b23 = *(const uint4*)(pb2 + 48);

    f32x4_t acc1 = {0.f, 0.f, 0.f, 0.f};
    acc1 = mfma16(a10, b10, acc1);
    acc1 = mfma16(a11, b11, acc1);
    acc1 = mfma16(a12, b12, acc1);
    acc1 = mfma16(a13, b13, acc1);
    f32x4_t acc2 = {0.f, 0.f, 0.f, 0.f};
    acc2 = mfma16(a20, b20, acc2);
    acc2 = mfma16(a21, b21, acc2);
    acc2 = mfma16(a22, b22, acc2);
    acc2 = mfma16(a23, b23, acc2);

    float p1 = sel4(acc1, m3);
    float p2 = sel4(acc2, m3);
    bool act1 = diag && (e1 < ecnt);
    bool act2 = diag && (e2 < ecnt);

    unsigned long long bl = __ballot(act1 && fabsf(p1 - 0.1f) < BL_MARGIN);
    while (bl) {
        int src = __ffsll((unsigned long long)bl) - 1; bl &= bl - 1ull;
        int rt = __shfl(r1, src, 64);
        int ct = __shfl(c1, src, 64);
        float2 xa = *(const float2*)(feat32 + (size_t)rt * 128 + lane * 2);
        float2 xb = *(const float2*)(feat32 + (size_t)ct * 128 + lane * 2);
        float s2 = xa.x * xb.x + xa.y * xb.y;
        #pragma unroll
        for (int off = 32; off; off >>= 1) s2 += __shfl_xor(s2, off, 64);
        float pf = s2 / (nrm[rt] * nrm[ct]);
        if (lane == src) p1 = pf;
    }
    unsigned long long bl2 = __ballot(act2 && fabsf(p2 - 0.1f) < BL_MARGIN);
    while (bl2) {
        int src = __ffsll((unsigned long long)bl2) - 1; bl2 &= bl2 - 1ull;
        int rt = __shfl(r2, src, 64);
        int ct = __shfl(c2, src, 64);
        float2 xa = *(const float2*)(feat32 + (size_t)rt * 128 + lane * 2);
        float2 xb = *(const float2*)(feat32 + (size_t)ct * 128 + lane * 2);
        float s2 = xa.x * xb.x + xa.y * xb.y;
        #pragma unroll
        for (int off = 32; off; off >>= 1) s2 += __shfl_xor(s2, off, 64);
        float pf = s2 / (nrm[rt] * nrm[ct]);
        if (lane == src) p2 = pf;
    }
    if (act1) {
        float kv = (p1 >= 0.1f) ? p1 : 0.0f;
        sims[e1] = kv;
        if (kv > 0.0f) atomicAdd(&deg1[r1], kv);
    }
    if (act2) {
        float kv = (p2 >= 0.1f) ? p2 : 0.0f;
        sims[e2] = kv;
        if (kv > 0.0f) atomicAdd(&deg1[r2], kv);
    }
}

// ---------------- GEMM bodies: UNSCALED outputs, W from global (L2-hot) --------
// R8: dinv2 scaling moved into the gather epilogues -> GEMMs are independent of
// the edge phase and fuse into its dispatch. No LDS, no barriers (heterogeneous
// blocks must not sync). W rows read coalesced (512B/row), L2-resident.

static __device__ inline void gemm128_body(int gid, const float* __restrict__ A,
    const float* __restrict__ W, float* __restrict__ out, int n) {
    const int TPN = 32;
    int group = threadIdx.x / TPN;            // 8 groups -> 32 nodes/block
    int tin   = threadIdx.x % TPN;
    int nid   = (gid * 8 + group) * 4;
    if (nid >= n) return;
    int dbase = tin * 4;
    int nm1 = n - 1;
    const float4* a0 = (const float4*)(A + (size_t)min(nid,     nm1) * 128);
    const float4* a1 = (const float4*)(A + (size_t)min(nid + 1, nm1) * 128);
    const float4* a2 = (const float4*)(A + (size_t)min(nid + 2, nm1) * 128);
    const float4* a3 = (const float4*)(A + (size_t)min(nid + 3, nm1) * 128);
    const float4* Wv = (const float4*)W;      // [128][128] -> row r: 32 float4
    float4 acc0 = {0,0,0,0}, acc1 = {0,0,0,0}, acc2 = {0,0,0,0}, acc3 = {0,0,0,0};
    #pragma unroll 2
    for (int k4 = 0; k4 < 32; ++k4) {
        float4 w0 = Wv[(k4 * 4 + 0) * 32 + tin];
        float4 w1 = Wv[(k4 * 4 + 1) * 32 + tin];
        float4 w2 = Wv[(k4 * 4 + 2) * 32 + tin];
        float4 w3 = Wv[(k4 * 4 + 3) * 32 + tin];
        float4 v0 = a0[k4], v1 = a1[k4], v2 = a2[k4], v3 = a3[k4];
        acc0.x += v0.x*w0.x + v0.y*w1.x + v0.z*w2.x + v0.w*w3.x;
        acc0.y += v0.x*w0.y + v0.y*w1.y + v0.z*w2.y + v0.w*w3.y;
        acc0.z += v0.x*w0.z + v0.y*w1.z + v0.z*w2.z + v0.w*w3.z;
        acc0.w += v0.x*w0.w + v0.y*w1.w + v0.z*w2.w + v0.w*w3.w;
        acc1.x += v1.x*w0.x + v1.y*w1.x + v1.z*w2.x + v1.w*w3.x;
        acc1.y += v1.x*w0.y + v1.y*w1.y + v1.z*w2.y + v1.w*w3.y;
        acc1.z += v1.x*w0.z + v1.y*w1.z + v1.z*w2.z + v1.w*w3.z;
        acc1.w += v1.x*w0.w + v1.y*w1.w + v1.z*w2.w + v1.w*w3.w;
        acc2.x += v2.x*w0.x + v2.y*w1.x + v2.z*w2.x + v2.w*w3.x;
        acc2.y += v2.x*w0.y + v2.y*w1.y + v2.z*w2.y + v2.w*w3.y;
        acc2.z += v2.x*w0.z + v2.y*w1.z + v2.z*w2.z + v2.w*w3.z;
        acc2.w += v2.x*w0.w + v2.y*w1.w + v2.z*w2.w + v2.w*w3.w;
        acc3.x += v3.x*w0.x + v3.y*w1.x + v3.z*w2.x + v3.w*w3.x;
        acc3.y += v3.x*w0.y + v3.y*w1.y + v3.z*w2.y + v3.w*w3.y;
        acc3.z += v3.x*w0.z + v3.y*w1.z + v3.z*w2.z + v3.w*w3.z;
        acc3.w += v3.x*w0.w + v3.y*w1.w + v3.z*w2.w + v3.w*w3.w;
    }
    float4 accs[4] = {acc0, acc1, acc2, acc3};
    #pragma unroll
    for (int i = 0; i < 4; ++i) {
        if (nid + i < n)
            *(float4*)(out + (size_t)(nid + i) * 128 + dbase) = accs[i];
    }
}

static __device__ inline void gemm64_body(int gid, const float* __restrict__ A,
    const float* __restrict__ W, u32* __restrict__ outhf, int n) {
    const int TPN = 16;
    int group = threadIdx.x / TPN;            // 16 groups -> 64 nodes/block
    int tin   = threadIdx.x % TPN;
    int nid   = (gid * 16 + group) * 4;
    if (nid >= n) return;
    int nm1 = n - 1;
    const float4* a0 = (const float4*)(A + (size_t)min(nid,     nm1) * 128);
    const float4* a1 = (const float4*)(A + (size_t)min(nid + 1, nm1) * 128);
    const float4* a2 = (const float4*)(A + (size_t)min(nid + 2, nm1) * 128);
    const float4* a3 = (const float4*)(A + (size_t)min(nid + 3, nm1) * 128);
    const float4* Wv = (const float4*)W;      // [128][64] -> row r: 16 float4
    float4 acc0 = {0,0,0,0}, acc1 = {0,0,0,0}, acc2 = {0,0,0,0}, acc3 = {0,0,0,0};
    #pragma unroll 2
    for (int k4 = 0; k4 < 32; ++k4) {
        float4 w0 = Wv[(k4 * 4 + 0) * 16 + tin];
        float4 w1 = Wv[(k4 * 4 + 1) * 16 + tin];
        float4 w2 = Wv[(k4 * 4 + 2) * 16 + tin];
        float4 w3 = Wv[(k4 * 4 + 3) * 16 + tin];
        float4 v0 = a0[k4], v1 = a1[k4], v2 = a2[k4], v3 = a3[k4];
        acc0.x += v0.x*w0.x + v0.y*w1.x + v0.z*w2.x + v0.w*w3.x;
        acc0.y += v0.x*w0.y + v0.y*w1.y + v0.z*w2.y + v0.w*w3.y;
        acc0.z += v0.x*w0.z + v0.y*w1.z + v0.z*w2.z + v0.w*w3.z;
        acc0.w += v0.x*w0.w + v0.y*w1.w + v0.z*w2.w + v0.w*w3.w;
        acc1.x += v1.x*w0.x + v1.y*w1.x + v1.z*w2.x + v1.w*w3.x;
        acc1.y += v1.x*w0.y + v1.y*w1.y + v1.z*w2.y + v1.w*w3.y;
        acc1.z += v1.x*w0.z + v1.y*w1.z + v1.z*w2.z + v1.w*w3.z;
        acc1.w += v1.x*w0.w + v1.y*w1.w + v1.z*w2.w + v1.w*w3.w;
        acc2.x += v2.x*w0.x + v2.y*w1.x + v2.z*w2.x + v2.w*w3.x;
        acc2.y += v2.x*w0.y + v2.y*w1.y + v2.z*w2.y + v2.w*w3.y;
        acc2.z += v2.x*w0.z + v2.y*w1.z + v2.z*w2.z + v2.w*w3.z;
        acc2.w += v2.x*w0.w + v2.y*w1.w + v2.z*w2.w + v2.w*w3.w;
        acc3.x += v3.x*w0.x + v3.y*w1.x + v3.z*w2.x + v3.w*w3.x;
        acc3.y += v3.x*w0.y + v3.y*w1.y + v3.z*w2.y + v3.w*w3.y;
        acc3.z += v3.x*w0.z + v3.y*w1.z + v3.z*w2.z + v3.w*w3.z;
        acc3.w += v3.x*w0.w + v3.y*w1.w + v3.z*w2.w + v3.w*w3.w;
    }
    float4 accs[4] = {acc0, acc1, acc2, acc3};
    #pragma unroll
    for (int i = 0; i < 4; ++i) {
        if (nid + i < n) {
            u32 o0 = pack_h2(accs[i].x, accs[i].y);
            u32 o1 = pack_h2(accs[i].z, accs[i].w);
            *(uint2*)(outhf + (size_t)(nid + i) * 32 + tin * 2)
                = make_uint2(o0, o1);
        }
    }
}

// ---------------- fused heterogeneous dispatches ----------------
// Every R-th block runs a GEMM body; the rest run edge-dot bodies. The
// latency-stalled edge waves and FMA-dense gemm waves co-schedule per CU.
__global__ __launch_bounds__(256) void fused1_k(const u32* __restrict__ fhf,
    const float* __restrict__ x, const int* __restrict__ rowAll,
    const int* __restrict__ colAll, const float* __restrict__ nrm,
    float* __restrict__ sims, float* __restrict__ deg1, int ecnt,
    const float* __restrict__ W1, float* __restrict__ hs, int n,
    int R, int nGemm) {
    int b = blockIdx.x;
    if ((b % R) == 0 && (b / R) < nGemm) {
        gemm128_body(b / R, x, W1, hs, n);
    } else {
        int e = b - min(b / R + 1, nGemm);
        edge_dot_body(e, fhf, x, rowAll, colAll, nrm, sims, deg1, ecnt);
    }
}

__global__ __launch_bounds__(256) void fused2_k(const u32* __restrict__ h2hf,
    const float* __restrict__ h2, const int* __restrict__ rowAll,
    const int* __restrict__ colAll, const float* __restrict__ nrm,
    float* __restrict__ sims, float* __restrict__ deg1, int ecnt,
    const float* __restrict__ W2, u32* __restrict__ g2shf, int n,
    int R, int nGemm) {
    int b = blockIdx.x;
    if ((b % R) == 0 && (b / R) < nGemm) {
        gemm64_body(b / R, h2, W2, g2shf, n);
    } else {
        int e = b - min(b / R + 1, nGemm);
        edge_dot_body(e, h2hf, h2, rowAll, colAll, nrm, sims, deg1, ecnt);
    }
}

// ---------------- edge phase B: vals + deg2 + IN-PLACE compaction --------------
// R8: kval aliases sims (in-place). Safe: one wave per node, wave-lockstep
// batch loads complete before the batch's stores, write head (kept count)
// <= read head, per-node segments disjoint.
__global__ __launch_bounds__(256) void edge_c_csr_k(float* __restrict__ simsv,
    const int* __restrict__ rowAll, const int* __restrict__ startAll,
    const int* __restrict__ cntAll, const float* __restrict__ deg1,
    int* __restrict__ krow, int* __restrict__ cntK, float* __restrict__ dinv2,
    float* __restrict__ cself, int n) {
    int wid  = (blockIdx.x * 256 + threadIdx.x) >> 6;
    int lane = threadIdx.x & 63;
    if (wid >= n) return;
    int s0 = startAll[wid], cnt = cntAll[wid];
    float degc = deg1[wid];
    float d1c = (degc > 0.0f) ? 1.0f / sqrtf(degc) : 0.0f;
    float vsum = 0.0f; int kc = 0;
    for (int jj = 0; jj < cnt; jj += 64) {
        int j = jj + lane;
        bool keep = false; int r = 0; float v = 0.0f;
        if (j < cnt) {
            float s = simsv[s0 + j];
            if (s > 0.0f) {
                r = rowAll[s0 + j];
                float dr = 1.0f / sqrtf(deg1[r]);     // deg1[r] >= s >= 0.1
                v = expf(dr * s * d1c);
                keep = true;
            }
        }
        unsigned long long m = __ballot(keep ? 1 : 0);
        if (keep) {
            int pre = __popcll(m & ((1ull << lane) - 1ull));
            simsv[s0 + kc + pre] = v;                 // in-place compacted val
            krow[s0 + kc + pre] = r;
            vsum += v;
        }
        kc += __popcll(m);
    }
    #pragma unroll
    for (int off = 32; off; off >>= 1) vsum += __shfl_xor(vsum, off, 64);
    if (lane == 0) {
        float ws_ = expf(1.0f / ((float)kc + 1.0f));   // self-loop weight
        float dg = ws_ + vsum;                         // always > 0
        float di = 1.0f / sqrtf(dg);
        dinv2[wid] = di;
        cself[wid] = di * ws_;
        cntK[wid]  = kc;
    }
}

// ---------------- fused gather epilogues (half-wave per node) ----------------
// R8: hs/g2s are UNSCALED; apply val*dinv2[row] per edge (dinv2 is a broadcast
// load, same addr across the half-wave, L2-resident) and cself*dinv2[wid] for
// the self term. Math identical to the pre-scaled form.

__global__ __launch_bounds__(256) void gather_ln_k(const float* __restrict__ hs,
    const int* __restrict__ krow, const float* __restrict__ kval,
    const int* __restrict__ startAll,
    const int* __restrict__ cntK, const float* __restrict__ dinv2,
    const float* __restrict__ cself, const float* __restrict__ bias,
    const float* __restrict__ g, const float* __restrict__ bln,
    float* __restrict__ outbuf, u32* __restrict__ outhf,
    float* __restrict__ nrm, float* __restrict__ deg1, int n) {
    int wid = (blockIdx.x * 256 + threadIdx.x) >> 5;
    int l   = threadIdx.x & 31;
    if (wid >= n) return;
    int s0 = startAll[wid], k = cntK[wid];
    if (l == 0) deg1[wid] = 0.0f;               // pre-zero for layer-2 edge_dot
    float4 acc = {0,0,0,0};
    int km1 = s0 + k - 1;
    for (int j0 = 0; j0 < k; j0 += 8) {
        int ri[8]; float wv[8];
        #pragma unroll
        for (int i = 0; i < 8; ++i) {
            int idx = min(s0 + j0 + i, km1);
            ri[i] = krow[idx]; wv[i] = kval[idx];
        }
        float dv[8];
        #pragma unroll
        for (int i = 0; i < 8; ++i) dv[i] = dinv2[ri[i]];
        float4 h[8];
        #pragma unroll
        for (int i = 0; i < 8; ++i)
            h[i] = *(const float4*)(hs + (size_t)ri[i] * 128 + l * 4);
        #pragma unroll
        for (int i = 0; i < 8; ++i) {
            float w = (j0 + i < k) ? wv[i] * dv[i] : 0.0f;
            acc.x += w * h[i].x; acc.y += w * h[i].y;
            acc.z += w * h[i].z; acc.w += w * h[i].w;
        }
    }
    float di = dinv2[wid], cs = cself[wid] * di;
    float4 hsv = *(const float4*)(hs + (size_t)wid * 128 + l * 4);
    float4 vb  = *(const float4*)(bias + l * 4);
    float x0 = di*acc.x + cs*hsv.x + vb.x;
    float x1 = di*acc.y + cs*hsv.y + vb.y;
    float x2 = di*acc.z + cs*hsv.z + vb.z;
    float x3 = di*acc.w + cs*hsv.w + vb.w;
    float s = x0 + x1 + x2 + x3;
    #pragma unroll
    for (int off = 16; off; off >>= 1) s += __shfl_xor(s, off, 64);
    float mu = s * (1.0f / 128.0f);
    float d0 = x0 - mu, d1 = x1 - mu, d2 = x2 - mu, d3 = x3 - mu;
    float vv = d0*d0 + d1*d1 + d2*d2 + d3*d3;
    #pragma unroll
    for (int off = 16; off; off >>= 1) vv += __shfl_xor(vv, off, 64);
    float rstd = 1.0f / sqrtf(vv * (1.0f / 128.0f) + LN_EPS);
    float4 vg  = *(const float4*)(g + l * 4);
    float4 vbl = *(const float4*)(bln + l * 4);
    float y0 = fmaxf(d0 * rstd * vg.x + vbl.x, 0.0f);
    float y1 = fmaxf(d1 * rstd * vg.y + vbl.y, 0.0f);
    float y2 = fmaxf(d2 * rstd * vg.z + vbl.z, 0.0f);
    float y3 = fmaxf(d3 * rstd * vg.w + vbl.w, 0.0f);
    float4 yo; yo.x = y0; yo.y = y1; yo.z = y2; yo.w = y3;
    *(float4*)(outbuf + (size_t)wid * 128 + l * 4) = yo;
    float ns = y0*y0 + y1*y1 + y2*y2 + y3*y3;
    #pragma unroll
    for (int off = 16; off; off >>= 1) ns += __shfl_xor(ns, off, 64);
    float nv = fmaxf(sqrtf(ns), EPSF);
    float inv = 1.0f / nv;
    uint2 oh; oh.x = pack_h2(y0 * inv, y1 * inv); oh.y = pack_h2(y2 * inv, y3 * inv);
    *(uint2*)(outhf + (size_t)wid * 64 + l * 2) = oh;
    if (l == 0) nrm[wid] = nv;
}

__global__ __launch_bounds__(256) void gather_lsm_hf_k(const u32* __restrict__ g2s,
    const int* __restrict__ krow, const float* __restrict__ kval,
    const int* __restrict__ startAll,
    const int* __restrict__ cntK, const float* __restrict__ dinv2,
    const float* __restrict__ cself, const float* __restrict__ b2,
    float* __restrict__ out, int n) {
    int wid = (blockIdx.x * 256 + threadIdx.x) >> 5;
    int l   = threadIdx.x & 31;
    if (wid >= n) return;
    int s0 = startAll[wid], k = cntK[wid];
    float acc0 = 0.f, acc1 = 0.f;
    int km1 = s0 + k - 1;
    for (int j0 = 0; j0 < k; j0 += 8) {
        int ri[8]; float wv[8];
        #pragma unroll
        for (int i = 0; i < 8; ++i) {
            int idx = min(s0 + j0 + i, km1);
            ri[i] = krow[idx]; wv[i] = kval[idx];
        }
        float dv[8];
        #pragma unroll
        for (int i = 0; i < 8; ++i) dv[i] = dinv2[ri[i]];
        u32 gv[8];
        #pragma unroll
        for (int i = 0; i < 8; ++i) gv[i] = g2s[(size_t)ri[i] * 32 + l];
        #pragma unroll
        for (int i = 0; i < 8; ++i) {
            float w = (j0 + i < k) ? wv[i] * dv[i] : 0.0f;
            acc0 += w * h2lo(gv[i]); acc1 += w * h2hi(gv[i]);
        }
    }
    float di = dinv2[wid], cs = cself[wid] * di;
    u32 gsu = g2s[(size_t)wid * 32 + l];
    float2 vb = *(const float2*)(b2 + l * 2);
    float v0 = di * acc0 + cs * h2lo(gsu) + vb.x;
    float v1 = di * acc1 + cs * h2hi(gsu) + vb.y;
    float m = fmaxf(v0, v1);
    #pragma unroll
    for (int off = 16; off; off >>= 1) m = fmaxf(m, __shfl_xor(m, off, 64));
    float e = expf(v0 - m) + expf(v1 - m);
    #pragma unroll
    for (int off = 16; off; off >>= 1) e += __shfl_xor(e, off, 64);
    float lse = m + logf(e);
    *(float2*)(out + (size_t)wid * 64 + l * 2) = make_float2(v0 - lse, v1 - lse);
}

// ---------------- launch ----------------

extern "C" void kernel_launch(void* const* d_in, const int* in_sizes, int n_in,
                              void* d_out, int out_size, void* d_ws, size_t ws_size,
                              hipStream_t stream) {
    (void)n_in; (void)out_size; (void)ws_size;
    const float* x   = (const float*)d_in[0];
    const int*   row = (const int*)d_in[1];
    const int*   col = (const int*)d_in[2];
    const float* W1  = (const float*)d_in[3];
    const float* b1  = (const float*)d_in[4];
    const float* lng = (const float*)d_in[5];
    const float* lnb = (const float*)d_in[6];
    const float* W2  = (const float*)d_in[7];
    const float* b2  = (const float*)d_in[8];
    float* out = (float*)d_out;

    const int N = in_sizes[0] / 128;
    const int E = in_sizes[1];

    int*   cntAll   = (int*)d_ws;
    int*   startAll = cntAll + N;
    int*   bcur     = startAll + N;            // 512 cursors (pad region to 1024)
    float* nrm      = (float*)(bcur + 1024);
    float* deg1     = nrm + N;                 // zeroed by cast_norm / gather_ln
    float* dinv2    = deg1 + N;
    float* cself    = dinv2 + N;
    int*   cntK     = (int*)(cself + N);
    int*   rowAll   = cntK + N;                // [E]
    int*   colAll   = rowAll + E;              // [E]
    float* simsv    = (float*)(colAll + E);    // [E] sims, then compacted kval
    int*   krow     = (int*)(simsv + E);       // [E] compacted rows
    u32*   fhf      = (u32*)(krow + E);        // [64N] fp16 units; reused as h2hf
    u32*   g2shf    = fhf + (size_t)64 * N;    // [32N]
    float* big      = (float*)(g2shf + (size_t)32 * N);
    float* hs       = big;                     // [128N] layer-1 UNSCALED x@W1
    float* h2       = big + (size_t)128 * N;   // [128N] layer-1 output (persists)
    int2*  ebuf     = (int2*)big;              // [NBKT*BCAP]=21MB CSR scratch
                                               // (dead before fused1 writes hs)

    const int waveBlocks  = (N + 3) / 4;
    const int halfBlocks  = (N + 7) / 8;
    const int flatBlocks  = (E + 127) / 128;   // 128 edges/block (4 waves)
    const int NB          = (N + 255) >> 8;

    const int nGemm1 = (N + 31) / 32;
    const int tot1   = flatBlocks + nGemm1;
    const int R1     = tot1 / nGemm1;          // >= 1
    const int nGemm2 = (N + 63) / 64;
    const int tot2   = flatBlocks + nGemm2;
    const int R2     = tot2 / nGemm2;

    // ---- one-time CSR build ----
    hipMemsetAsync(bcur, 0, NBKT * sizeof(int), stream);
    binfill_k<<<(E + CHUNK - 1) / CHUNK, 256, 0, stream>>>(row, col, bcur, ebuf, E);
    bucket_csr_k<<<NB, 256, 0, stream>>>(ebuf, bcur, startAll, cntAll, rowAll,
                                         colAll, N);

    // ================= layer 1 =================
    cast_norm_k<<<waveBlocks, 256, 0, stream>>>(x, fhf, nrm, deg1, N);
    fused1_k<<<tot1, 256, 0, stream>>>(fhf, x, rowAll, colAll, nrm, simsv, deg1, E,
                                       W1, hs, N, R1, nGemm1);
    edge_c_csr_k<<<waveBlocks, 256, 0, stream>>>(simsv, rowAll, startAll, cntAll,
                                                 deg1, krow, cntK, dinv2, cself, N);
    gather_ln_k<<<halfBlocks, 256, 0, stream>>>(hs, krow, simsv, startAll, cntK,
                                                dinv2, cself, b1, lng, lnb,
                                                h2, fhf, nrm, deg1, N);

    // ================= layer 2 =================
    fused2_k<<<tot2, 256, 0, stream>>>(fhf, h2, rowAll, colAll, nrm, simsv, deg1, E,
                                       W2, g2shf, N, R2, nGemm2);
    edge_c_csr_k<<<waveBlocks, 256, 0, stream>>>(simsv, rowAll, startAll, cntAll,
                                                 deg1, krow, cntK, dinv2, cself, N);
    gather_lsm_hf_k<<<halfBlocks, 256, 0, stream>>>(g2shf, krow, simsv, startAll,
                                                    cntK, dinv2, cself, b2, out, N);
}

// Round 9
// 615.353 us; speedup vs baseline: 1.4170x; 1.4170x over previous
//
#include <hip/hip_runtime.h>
#include <math.h>

#define EPSF 1e-8f
#define LN_EPS 1e-5f
#define BL_MARGIN 0.002f   // > bound on fp16 unit-vector cosine-sim error (~1.5e-3)

#define BKT_SH 8           // 256 cols per bucket
#define NBKT 512           // needs N <= 131072
#define CHUNK 2048         // edges per binfill block
// Per-bucket edges ~ Binomial: mean = 256 cols x (E/N=16) = 4096, sigma ~ 64.
// R5 CRASH POST-MORTEM: BCAP must exceed mean+16sigma (3840 < 4096 faulted).
#define BCAP 5120

typedef unsigned int  u32;
typedef unsigned short u16;
typedef _Float16 h2_t __attribute__((ext_vector_type(2)));
typedef _Float16 half8_t __attribute__((ext_vector_type(8)));
typedef float f32x4_t __attribute__((ext_vector_type(4)));

static __device__ inline u32 pack_h2(float a, float b) {
    h2_t h; h.x = (_Float16)a; h.y = (_Float16)b;
    return __builtin_bit_cast(u32, h);
}
static __device__ inline float h2lo(u32 u) {
    return (float)__builtin_bit_cast(h2_t, u).x;
}
static __device__ inline float h2hi(u32 u) {
    return (float)__builtin_bit_cast(h2_t, u).y;
}

// D = A(16x32 f16) * B(32x16 f16) + C, fp32 accumulate.
static __device__ inline f32x4_t mfma16(uint4 a, uint4 b, f32x4_t c) {
    return __builtin_amdgcn_mfma_f32_16x16x32_f16(
        __builtin_bit_cast(half8_t, a), __builtin_bit_cast(half8_t, b), c, 0, 0, 0);
}
static __device__ inline float sel4(f32x4_t a, int m) {
    return m == 0 ? a[0] : m == 1 ? a[1] : m == 2 ? a[2] : a[3];
}

// ---------------- layer-1 prep: norms + UNIT-vector fp16 cast (+deg1 zero) -----
__global__ __launch_bounds__(256) void cast_norm_k(const float* __restrict__ feat,
    u32* __restrict__ fhf, float* __restrict__ nrm, float* __restrict__ deg1, int n) {
    int wid  = (blockIdx.x * 256 + threadIdx.x) >> 6;
    int lane = threadIdx.x & 63;
    if (wid >= n) return;
    float2 v = *(const float2*)(feat + (size_t)wid * 128 + lane * 2);
    float s = v.x * v.x + v.y * v.y;
    #pragma unroll
    for (int off = 32; off; off >>= 1) s += __shfl_xor(s, off, 64);
    float nv = fmaxf(sqrtf(s), EPSF);
    float inv = 1.0f / nv;
    fhf[(size_t)wid * 64 + lane] = pack_h2(v.x * inv, v.y * inv);
    if (lane == 0) { nrm[wid] = nv; deg1[wid] = 0.0f; }
}

// ---------------- one-time CSR build: fixed-capacity bucketed sort ----------------
__global__ __launch_bounds__(256) void binfill_k(const int* __restrict__ row,
    const int* __restrict__ col, int* __restrict__ bcur,
    int2* __restrict__ ebuf, int ecnt) {
    __shared__ int lc[NBKT], ls[NBKT], cur[NBKT], gbase[NBKT];
    __shared__ int2 pairs[CHUNK];
    __shared__ int dstv[CHUNK];
    int t = threadIdx.x;
    int e0 = blockIdx.x * CHUNK;
    int m = min(CHUNK, ecnt - e0);
    lc[t] = 0; lc[t + 256] = 0; cur[t] = 0; cur[t + 256] = 0;
    __syncthreads();
    int myc[CHUNK / 256], myr[CHUNK / 256];
    #pragma unroll
    for (int i = 0; i < CHUNK / 256; ++i) {
        int idx = t + i * 256;
        if (idx < m) {
            myc[i] = col[e0 + idx];
            myr[i] = row[e0 + idx];
            atomicAdd(&lc[myc[i] >> BKT_SH], 1);
        }
    }
    __syncthreads();
    int v0 = lc[t], v1 = lc[t + 256];
    ls[t] = v0; ls[t + 256] = v1; __syncthreads();
    for (int off = 1; off < 256; off <<= 1) {
        int a0 = (t >= off) ? ls[t - off] : 0;
        int a1 = (t >= off) ? ls[256 + t - off] : 0;
        __syncthreads();
        ls[t] += a0; ls[t + 256] += a1;
        __syncthreads();
    }
    int h0 = ls[255];
    int e0x = ls[t] - v0;
    int e1x = ls[t + 256] - v1 + h0;
    __syncthreads();
    ls[t] = e0x; ls[t + 256] = e1x;
    if (v0) gbase[t] = atomicAdd(&bcur[t], v0);
    if (v1) gbase[t + 256] = atomicAdd(&bcur[t + 256], v1);
    __syncthreads();
    #pragma unroll
    for (int i = 0; i < CHUNK / 256; ++i) {
        int idx = t + i * 256;
        if (idx < m) {
            int b = myc[i] >> BKT_SH;
            int s = ls[b] + atomicAdd(&cur[b], 1);
            pairs[s] = make_int2(myc[i], myr[i]);
            int pos = gbase[b] + (s - ls[b]);
            dstv[s]  = (pos < BCAP) ? (b * BCAP + pos) : -1;
        }
    }
    __syncthreads();
    for (int s = t; s < m; s += 256) {
        int d = dstv[s];
        if (d >= 0) ebuf[d] = pairs[s];
    }
}

__global__ __launch_bounds__(256) void bucket_csr_k(const int2* __restrict__ ebuf,
    const int* __restrict__ bcur, int* __restrict__ startAll,
    int* __restrict__ cntAll, int* __restrict__ rowAll, int* __restrict__ colAll,
    int n) {
    __shared__ int sc[NBKT];
    __shared__ int cnt[256], lst[256], cur[256];
    __shared__ int rowbuf[BCAP];
    int b = blockIdx.x, t = threadIdx.x;
    int c0 = b << BKT_SH;
    int s0v = min(bcur[t], BCAP), s1v = min(bcur[t + 256], BCAP);
    sc[t] = s0v; sc[t + 256] = s1v; __syncthreads();
    for (int off = 1; off < 256; off <<= 1) {
        int a0 = (t >= off) ? sc[t - off] : 0;
        int a1 = (t >= off) ? sc[256 + t - off] : 0;
        __syncthreads();
        sc[t] += a0; sc[t + 256] += a1;
        __syncthreads();
    }
    int m  = min(bcur[b], BCAP);
    int g0 = ((b >= 256) ? sc[255] : 0) + sc[b] - m;
    size_t ebase = (size_t)b * BCAP;
    cnt[t] = 0; cur[t] = 0;
    __syncthreads();
    for (int i = t; i < m; i += 256)
        atomicAdd(&cnt[ebuf[ebase + i].x - c0], 1);
    __syncthreads();
    int v = cnt[t];
    lst[t] = v; __syncthreads();
    for (int off = 1; off < 256; off <<= 1) {
        int a = (t >= off) ? lst[t - off] : 0;
        __syncthreads();
        lst[t] += a;
        __syncthreads();
    }
    int ex = lst[t] - v;
    __syncthreads();
    lst[t] = ex;
    __syncthreads();
    int c = c0 + t;
    if (c < n) { startAll[c] = g0 + lst[t]; cntAll[c] = cnt[t]; }
    for (int i = t; i < m; i += 256) {
        int2 p = ebuf[ebase + i];
        int ci = p.x - c0;
        int pos = lst[ci] + atomicAdd(&cur[ci], 1);
        rowbuf[pos] = p.y;
    }
    __syncthreads();
    for (int i = t; i < m; i += 256)
        rowAll[g0 + i] = rowbuf[i];
    __syncthreads();
    {
        int base = lst[t], cn = cnt[t], cc = c0 + t;
        for (int k2 = 0; k2 < cn; ++k2) rowbuf[base + k2] = cc;
    }
    __syncthreads();
    for (int i = t; i < m; i += 256)
        colAll[g0 + i] = rowbuf[i];
}

// ---------------- edge-dot body (flat edge-parallel MFMA dots) ----------------
// R1-R3: pinned at ~91us; per-CU outstanding-miss x latency floor for the
// 1.6M x 256B random gather. Its idle VALU/occupancy slack hosts the fused
// GEMM blocks (fused1_k/fused2_k).
static __device__ inline void edge_dot_body(int ewk, const u32* __restrict__ fhf,
    const float* __restrict__ feat32, const int* __restrict__ rowAll,
    const int* __restrict__ colAll, const float* __restrict__ nrm,
    float* __restrict__ sims, float* __restrict__ deg1, int ecnt) {
    int lane = threadIdx.x & 63;
    int e0 = (ewk * 4 + (int)(threadIdx.x >> 6)) * 32;
    if (e0 >= ecnt) return;
    int lr = lane & 15, kq = lane >> 4;
    bool diag = (kq == (lr >> 2));
    int m3 = lane & 3;
    int em1 = ecnt - 1;

    int e1 = e0 + lr, e2 = e0 + 16 + lr;
    int e1c = min(e1, em1), e2c = min(e2, em1);
    int r1 = rowAll[e1c], c1 = colAll[e1c];
    int r2 = rowAll[e2c], c2 = colAll[e2c];
    const u32* pa1 = fhf + (size_t)c1 * 64 + kq * 4;
    const u32* pb1 = fhf + (size_t)r1 * 64 + kq * 4;
    const u32* pa2 = fhf + (size_t)c2 * 64 + kq * 4;
    const u32* pb2 = fhf + (size_t)r2 * 64 + kq * 4;
    uint4 a10 = *(const uint4*)(pa1);
    uint4 a11 = *(const uint4*)(pa1 + 16);
    uint4 a12 = *(const uint4*)(pa1 + 32);
    uint4 a13 = *(const uint4*)(pa1 + 48);
    uint4 b10 = *(const uint4*)(pb1);
    uint4 b11 = *(const uint4*)(pb1 + 16);
    uint4 b12 = *(const uint4*)(pb1 + 32);
    uint4 b13 = *(const uint4*)(pb1 + 48);
    uint4 a20 = *(const uint4*)(pa2);
    uint4 a21 = *(const uint4*)(pa2 + 16);
    uint4 a22 = *(const uint4*)(pa2 + 32);
    uint4 a23 = *(const uint4*)(pa2 + 48);
    uint4 b20 = *(const uint4*)(pb2);
    uint4 b21 = *(const uint4*)(pb2 + 16);
    uint4 b22 = *(const uint4*)(pb2 + 32);
    uint4 b23 = *(const uint4*)(pb2 + 48);

    f32x4_t acc1 = {0.f, 0.f, 0.f, 0.f};
    acc1 = mfma16(a10, b10, acc1);
    acc1 = mfma16(a11, b11, acc1);
    acc1 = mfma16(a12, b12, acc1);
    acc1 = mfma16(a13, b13, acc1);
    f32x4_t acc2 = {0.f, 0.f, 0.f, 0.f};
    acc2 = mfma16(a20, b20, acc2);
    acc2 = mfma16(a21, b21, acc2);
    acc2 = mfma16(a22, b22, acc2);
    acc2 = mfma16(a23, b23, acc2);

    float p1 = sel4(acc1, m3);
    float p2 = sel4(acc2, m3);
    bool act1 = diag && (e1 < ecnt);
    bool act2 = diag && (e2 < ecnt);

    unsigned long long bl = __ballot(act1 && fabsf(p1 - 0.1f) < BL_MARGIN);
    while (bl) {
        int src = __ffsll((unsigned long long)bl) - 1; bl &= bl - 1ull;
        int rt = __shfl(r1, src, 64);
        int ct = __shfl(c1, src, 64);
        float2 xa = *(const float2*)(feat32 + (size_t)rt * 128 + lane * 2);
        float2 xb = *(const float2*)(feat32 + (size_t)ct * 128 + lane * 2);
        float s2 = xa.x * xb.x + xa.y * xb.y;
        #pragma unroll
        for (int off = 32; off; off >>= 1) s2 += __shfl_xor(s2, off, 64);
        float pf = s2 / (nrm[rt] * nrm[ct]);
        if (lane == src) p1 = pf;
    }
    unsigned long long bl2 = __ballot(act2 && fabsf(p2 - 0.1f) < BL_MARGIN);
    while (bl2) {
        int src = __ffsll((unsigned long long)bl2) - 1; bl2 &= bl2 - 1ull;
        int rt = __shfl(r2, src, 64);
        int ct = __shfl(c2, src, 64);
        float2 xa = *(const float2*)(feat32 + (size_t)rt * 128 + lane * 2);
        float2 xb = *(const float2*)(feat32 + (size_t)ct * 128 + lane * 2);
        float s2 = xa.x * xb.x + xa.y * xb.y;
        #pragma unroll
        for (int off = 32; off; off >>= 1) s2 += __shfl_xor(s2, off, 64);
        float pf = s2 / (nrm[rt] * nrm[ct]);
        if (lane == src) p2 = pf;
    }
    if (act1) {
        float kv = (p1 >= 0.1f) ? p1 : 0.0f;
        sims[e1] = kv;
        if (kv > 0.0f) atomicAdd(&deg1[r1], kv);
    }
    if (act2) {
        float kv = (p2 >= 0.1f) ? p2 : 0.0f;
        sims[e2] = kv;
        if (kv > 0.0f) atomicAdd(&deg1[r2], kv);
    }
}

// ---------------- GEMM bodies: UNSCALED outputs, W from global (L2-hot) --------
// dinv2 scaling moved into the gather epilogues -> GEMMs are independent of
// the edge phase and fuse into its dispatch. No LDS, no barriers.

static __device__ inline void gemm128_body(int gid, const float* __restrict__ A,
    const float* __restrict__ W, float* __restrict__ out, int n) {
    const int TPN = 32;
    int group = threadIdx.x / TPN;            // 8 groups -> 32 nodes/block
    int tin   = threadIdx.x % TPN;
    int nid   = (gid * 8 + group) * 4;
    if (nid >= n) return;
    int dbase = tin * 4;
    int nm1 = n - 1;
    const float4* a0 = (const float4*)(A + (size_t)min(nid,     nm1) * 128);
    const float4* a1 = (const float4*)(A + (size_t)min(nid + 1, nm1) * 128);
    const float4* a2 = (const float4*)(A + (size_t)min(nid + 2, nm1) * 128);
    const float4* a3 = (const float4*)(A + (size_t)min(nid + 3, nm1) * 128);
    const float4* Wv = (const float4*)W;      // [128][128] -> row r: 32 float4
    float4 acc0 = {0,0,0,0}, acc1 = {0,0,0,0}, acc2 = {0,0,0,0}, acc3 = {0,0,0,0};
    #pragma unroll 2
    for (int k4 = 0; k4 < 32; ++k4) {
        float4 w0 = Wv[(k4 * 4 + 0) * 32 + tin];
        float4 w1 = Wv[(k4 * 4 + 1) * 32 + tin];
        float4 w2 = Wv[(k4 * 4 + 2) * 32 + tin];
        float4 w3 = Wv[(k4 * 4 + 3) * 32 + tin];
        float4 v0 = a0[k4], v1 = a1[k4], v2 = a2[k4], v3 = a3[k4];
        acc0.x += v0.x*w0.x + v0.y*w1.x + v0.z*w2.x + v0.w*w3.x;
        acc0.y += v0.x*w0.y + v0.y*w1.y + v0.z*w2.y + v0.w*w3.y;
        acc0.z += v0.x*w0.z + v0.y*w1.z + v0.z*w2.z + v0.w*w3.z;
        acc0.w += v0.x*w0.w + v0.y*w1.w + v0.z*w2.w + v0.w*w3.w;
        acc1.x += v1.x*w0.x + v1.y*w1.x + v1.z*w2.x + v1.w*w3.x;
        acc1.y += v1.x*w0.y + v1.y*w1.y + v1.z*w2.y + v1.w*w3.y;
        acc1.z += v1.x*w0.z + v1.y*w1.z + v1.z*w2.z + v1.w*w3.z;
        acc1.w += v1.x*w0.w + v1.y*w1.w + v1.z*w2.w + v1.w*w3.w;
        acc2.x += v2.x*w0.x + v2.y*w1.x + v2.z*w2.x + v2.w*w3.x;
        acc2.y += v2.x*w0.y + v2.y*w1.y + v2.z*w2.y + v2.w*w3.y;
        acc2.z += v2.x*w0.z + v2.y*w1.z + v2.z*w2.z + v2.w*w3.z;
        acc2.w += v2.x*w0.w + v2.y*w1.w + v2.z*w2.w + v2.w*w3.w;
        acc3.x += v3.x*w0.x + v3.y*w1.x + v3.z*w2.x + v3.w*w3.x;
        acc3.y += v3.x*w0.y + v3.y*w1.y + v3.z*w2.y + v3.w*w3.y;
        acc3.z += v3.x*w0.z + v3.y*w1.z + v3.z*w2.z + v3.w*w3.z;
        acc3.w += v3.x*w0.w + v3.y*w1.w + v3.z*w2.w + v3.w*w3.w;
    }
    float4 accs[4] = {acc0, acc1, acc2, acc3};
    #pragma unroll
    for (int i = 0; i < 4; ++i) {
        if (nid + i < n)
            *(float4*)(out + (size_t)(nid + i) * 128 + dbase) = accs[i];
    }
}

static __device__ inline void gemm64_body(int gid, const float* __restrict__ A,
    const float* __restrict__ W, u32* __restrict__ outhf, int n) {
    const int TPN = 16;
    int group = threadIdx.x / TPN;            // 16 groups -> 64 nodes/block
    int tin   = threadIdx.x % TPN;
    int nid   = (gid * 16 + group) * 4;
    if (nid >= n) return;
    int nm1 = n - 1;
    const float4* a0 = (const float4*)(A + (size_t)min(nid,     nm1) * 128);
    const float4* a1 = (const float4*)(A + (size_t)min(nid + 1, nm1) * 128);
    const float4* a2 = (const float4*)(A + (size_t)min(nid + 2, nm1) * 128);
    const float4* a3 = (const float4*)(A + (size_t)min(nid + 3, nm1) * 128);
    const float4* Wv = (const float4*)W;      // [128][64] -> row r: 16 float4
    float4 acc0 = {0,0,0,0}, acc1 = {0,0,0,0}, acc2 = {0,0,0,0}, acc3 = {0,0,0,0};
    #pragma unroll 2
    for (int k4 = 0; k4 < 32; ++k4) {
        float4 w0 = Wv[(k4 * 4 + 0) * 16 + tin];
        float4 w1 = Wv[(k4 * 4 + 1) * 16 + tin];
        float4 w2 = Wv[(k4 * 4 + 2) * 16 + tin];
        float4 w3 = Wv[(k4 * 4 + 3) * 16 + tin];
        float4 v0 = a0[k4], v1 = a1[k4], v2 = a2[k4], v3 = a3[k4];
        acc0.x += v0.x*w0.x + v0.y*w1.x + v0.z*w2.x + v0.w*w3.x;
        acc0.y += v0.x*w0.y + v0.y*w1.y + v0.z*w2.y + v0.w*w3.y;
        acc0.z += v0.x*w0.z + v0.y*w1.z + v0.z*w2.z + v0.w*w3.z;
        acc0.w += v0.x*w0.w + v0.y*w1.w + v0.z*w2.w + v0.w*w3.w;
        acc1.x += v1.x*w0.x + v1.y*w1.x + v1.z*w2.x + v1.w*w3.x;
        acc1.y += v1.x*w0.y + v1.y*w1.y + v1.z*w2.y + v1.w*w3.y;
        acc1.z += v1.x*w0.z + v1.y*w1.z + v1.z*w2.z + v1.w*w3.z;
        acc1.w += v1.x*w0.w + v1.y*w1.w + v1.z*w2.w + v1.w*w3.w;
        acc2.x += v2.x*w0.x + v2.y*w1.x + v2.z*w2.x + v2.w*w3.x;
        acc2.y += v2.x*w0.y + v2.y*w1.y + v2.z*w2.y + v2.w*w3.y;
        acc2.z += v2.x*w0.z + v2.y*w1.z + v2.z*w2.z + v2.w*w3.z;
        acc2.w += v2.x*w0.w + v2.y*w1.w + v2.z*w2.w + v2.w*w3.w;
        acc3.x += v3.x*w0.x + v3.y*w1.x + v3.z*w2.x + v3.w*w3.x;
        acc3.y += v3.x*w0.y + v3.y*w1.y + v3.z*w2.y + v3.w*w3.y;
        acc3.z += v3.x*w0.z + v3.y*w1.z + v3.z*w2.z + v3.w*w3.z;
        acc3.w += v3.x*w0.w + v3.y*w1.w + v3.z*w2.w + v3.w*w3.w;
    }
    float4 accs[4] = {acc0, acc1, acc2, acc3};
    #pragma unroll
    for (int i = 0; i < 4; ++i) {
        if (nid + i < n) {
            u32 o0 = pack_h2(accs[i].x, accs[i].y);
            u32 o1 = pack_h2(accs[i].z, accs[i].w);
            *(uint2*)(outhf + (size_t)(nid + i) * 32 + tin * 2)
                = make_uint2(o0, o1);
        }
    }
}

// ---------------- fused heterogeneous dispatches ----------------
// Every R-th block runs a GEMM body; the rest run edge-dot bodies.
// R9 POST-MORTEM FIX: blocks round-robin across the 8 XCDs by blockIdx%8.
// R8 had R2 = 8 -> ALL gemm blocks landed on ONE XCD (1563 blocks / 32 CUs,
// ~49-deep serial tail) -> fused2 = 408us at 12.7% occupancy (1 block/CU avg).
// R must be COPRIME with 8 (odd) so gemm blocks spread across all XCDs.
__global__ __launch_bounds__(256) void fused1_k(const u32* __restrict__ fhf,
    const float* __restrict__ x, const int* __restrict__ rowAll,
    const int* __restrict__ colAll, const float* __restrict__ nrm,
    float* __restrict__ sims, float* __restrict__ deg1, int ecnt,
    const float* __restrict__ W1, float* __restrict__ hs, int n,
    int R, int nGemm) {
    int b = blockIdx.x;
    if ((b % R) == 0 && (b / R) < nGemm) {
        gemm128_body(b / R, x, W1, hs, n);
    } else {
        int e = b - min(b / R + 1, nGemm);
        edge_dot_body(e, fhf, x, rowAll, colAll, nrm, sims, deg1, ecnt);
    }
}

__global__ __launch_bounds__(256) void fused2_k(const u32* __restrict__ h2hf,
    const float* __restrict__ h2, const int* __restrict__ rowAll,
    const int* __restrict__ colAll, const float* __restrict__ nrm,
    float* __restrict__ sims, float* __restrict__ deg1, int ecnt,
    const float* __restrict__ W2, u32* __restrict__ g2shf, int n,
    int R, int nGemm) {
    int b = blockIdx.x;
    if ((b % R) == 0 && (b / R) < nGemm) {
        gemm64_body(b / R, h2, W2, g2shf, n);
    } else {
        int e = b - min(b / R + 1, nGemm);
        edge_dot_body(e, h2hf, h2, rowAll, colAll, nrm, sims, deg1, ecnt);
    }
}

// ---------------- edge phase B: vals + deg2 + IN-PLACE compaction --------------
// kval aliases sims (in-place). Safe: one wave per node, wave-lockstep batch
// loads complete before the batch's stores, write head <= read head.
__global__ __launch_bounds__(256) void edge_c_csr_k(float* __restrict__ simsv,
    const int* __restrict__ rowAll, const int* __restrict__ startAll,
    const int* __restrict__ cntAll, const float* __restrict__ deg1,
    int* __restrict__ krow, int* __restrict__ cntK, float* __restrict__ dinv2,
    float* __restrict__ cself, int n) {
    int wid  = (blockIdx.x * 256 + threadIdx.x) >> 6;
    int lane = threadIdx.x & 63;
    if (wid >= n) return;
    int s0 = startAll[wid], cnt = cntAll[wid];
    float degc = deg1[wid];
    float d1c = (degc > 0.0f) ? 1.0f / sqrtf(degc) : 0.0f;
    float vsum = 0.0f; int kc = 0;
    for (int jj = 0; jj < cnt; jj += 64) {
        int j = jj + lane;
        bool keep = false; int r = 0; float v = 0.0f;
        if (j < cnt) {
            float s = simsv[s0 + j];
            if (s > 0.0f) {
                r = rowAll[s0 + j];
                float dr = 1.0f / sqrtf(deg1[r]);     // deg1[r] >= s >= 0.1
                v = expf(dr * s * d1c);
                keep = true;
            }
        }
        unsigned long long m = __ballot(keep ? 1 : 0);
        if (keep) {
            int pre = __popcll(m & ((1ull << lane) - 1ull));
            simsv[s0 + kc + pre] = v;                 // in-place compacted val
            krow[s0 + kc + pre] = r;
            vsum += v;
        }
        kc += __popcll(m);
    }
    #pragma unroll
    for (int off = 32; off; off >>= 1) vsum += __shfl_xor(vsum, off, 64);
    if (lane == 0) {
        float ws_ = expf(1.0f / ((float)kc + 1.0f));   // self-loop weight
        float dg = ws_ + vsum;                         // always > 0
        float di = 1.0f / sqrtf(dg);
        dinv2[wid] = di;
        cself[wid] = di * ws_;
        cntK[wid]  = kc;
    }
}

// ---------------- fused gather epilogues (half-wave per node) ----------------
// hs/g2s are UNSCALED; apply val*dinv2[row] per edge and cself*dinv2[wid] for
// the self term. Math identical to the pre-scaled form.

__global__ __launch_bounds__(256) void gather_ln_k(const float* __restrict__ hs,
    const int* __restrict__ krow, const float* __restrict__ kval,
    const int* __restrict__ startAll,
    const int* __restrict__ cntK, const float* __restrict__ dinv2,
    const float* __restrict__ cself, const float* __restrict__ bias,
    const float* __restrict__ g, const float* __restrict__ bln,
    float* __restrict__ outbuf, u32* __restrict__ outhf,
    float* __restrict__ nrm, float* __restrict__ deg1, int n) {
    int wid = (blockIdx.x * 256 + threadIdx.x) >> 5;
    int l   = threadIdx.x & 31;
    if (wid >= n) return;
    int s0 = startAll[wid], k = cntK[wid];
    if (l == 0) deg1[wid] = 0.0f;               // pre-zero for layer-2 edge_dot
    float4 acc = {0,0,0,0};
    int km1 = s0 + k - 1;
    for (int j0 = 0; j0 < k; j0 += 8) {
        int ri[8]; float wv[8];
        #pragma unroll
        for (int i = 0; i < 8; ++i) {
            int idx = min(s0 + j0 + i, km1);
            ri[i] = krow[idx]; wv[i] = kval[idx];
        }
        float dv[8];
        #pragma unroll
        for (int i = 0; i < 8; ++i) dv[i] = dinv2[ri[i]];
        float4 h[8];
        #pragma unroll
        for (int i = 0; i < 8; ++i)
            h[i] = *(const float4*)(hs + (size_t)ri[i] * 128 + l * 4);
        #pragma unroll
        for (int i = 0; i < 8; ++i) {
            float w = (j0 + i < k) ? wv[i] * dv[i] : 0.0f;
            acc.x += w * h[i].x; acc.y += w * h[i].y;
            acc.z += w * h[i].z; acc.w += w * h[i].w;
        }
    }
    float di = dinv2[wid], cs = cself[wid] * di;
    float4 hsv = *(const float4*)(hs + (size_t)wid * 128 + l * 4);
    float4 vb  = *(const float4*)(bias + l * 4);
    float x0 = di*acc.x + cs*hsv.x + vb.x;
    float x1 = di*acc.y + cs*hsv.y + vb.y;
    float x2 = di*acc.z + cs*hsv.z + vb.z;
    float x3 = di*acc.w + cs*hsv.w + vb.w;
    float s = x0 + x1 + x2 + x3;
    #pragma unroll
    for (int off = 16; off; off >>= 1) s += __shfl_xor(s, off, 64);
    float mu = s * (1.0f / 128.0f);
    float d0 = x0 - mu, d1 = x1 - mu, d2 = x2 - mu, d3 = x3 - mu;
    float vv = d0*d0 + d1*d1 + d2*d2 + d3*d3;
    #pragma unroll
    for (int off = 16; off; off >>= 1) vv += __shfl_xor(vv, off, 64);
    float rstd = 1.0f / sqrtf(vv * (1.0f / 128.0f) + LN_EPS);
    float4 vg  = *(const float4*)(g + l * 4);
    float4 vbl = *(const float4*)(bln + l * 4);
    float y0 = fmaxf(d0 * rstd * vg.x + vbl.x, 0.0f);
    float y1 = fmaxf(d1 * rstd * vg.y + vbl.y, 0.0f);
    float y2 = fmaxf(d2 * rstd * vg.z + vbl.z, 0.0f);
    float y3 = fmaxf(d3 * rstd * vg.w + vbl.w, 0.0f);
    float4 yo; yo.x = y0; yo.y = y1; yo.z = y2; yo.w = y3;
    *(float4*)(outbuf + (size_t)wid * 128 + l * 4) = yo;
    float ns = y0*y0 + y1*y1 + y2*y2 + y3*y3;
    #pragma unroll
    for (int off = 16; off; off >>= 1) ns += __shfl_xor(ns, off, 64);
    float nv = fmaxf(sqrtf(ns), EPSF);
    float inv = 1.0f / nv;
    uint2 oh; oh.x = pack_h2(y0 * inv, y1 * inv); oh.y = pack_h2(y2 * inv, y3 * inv);
    *(uint2*)(outhf + (size_t)wid * 64 + l * 2) = oh;
    if (l == 0) nrm[wid] = nv;
}

__global__ __launch_bounds__(256) void gather_lsm_hf_k(const u32* __restrict__ g2s,
    const int* __restrict__ krow, const float* __restrict__ kval,
    const int* __restrict__ startAll,
    const int* __restrict__ cntK, const float* __restrict__ dinv2,
    const float* __restrict__ cself, const float* __restrict__ b2,
    float* __restrict__ out, int n) {
    int wid = (blockIdx.x * 256 + threadIdx.x) >> 5;
    int l   = threadIdx.x & 31;
    if (wid >= n) return;
    int s0 = startAll[wid], k = cntK[wid];
    float acc0 = 0.f, acc1 = 0.f;
    int km1 = s0 + k - 1;
    for (int j0 = 0; j0 < k; j0 += 8) {
        int ri[8]; float wv[8];
        #pragma unroll
        for (int i = 0; i < 8; ++i) {
            int idx = min(s0 + j0 + i, km1);
            ri[i] = krow[idx]; wv[i] = kval[idx];
        }
        float dv[8];
        #pragma unroll
        for (int i = 0; i < 8; ++i) dv[i] = dinv2[ri[i]];
        u32 gv[8];
        #pragma unroll
        for (int i = 0; i < 8; ++i) gv[i] = g2s[(size_t)ri[i] * 32 + l];
        #pragma unroll
        for (int i = 0; i < 8; ++i) {
            float w = (j0 + i < k) ? wv[i] * dv[i] : 0.0f;
            acc0 += w * h2lo(gv[i]); acc1 += w * h2hi(gv[i]);
        }
    }
    float di = dinv2[wid], cs = cself[wid] * di;
    u32 gsu = g2s[(size_t)wid * 32 + l];
    float2 vb = *(const float2*)(b2 + l * 2);
    float v0 = di * acc0 + cs * h2lo(gsu) + vb.x;
    float v1 = di * acc1 + cs * h2hi(gsu) + vb.y;
    float m = fmaxf(v0, v1);
    #pragma unroll
    for (int off = 16; off; off >>= 1) m = fmaxf(m, __shfl_xor(m, off, 64));
    float e = expf(v0 - m) + expf(v1 - m);
    #pragma unroll
    for (int off = 16; off; off >>= 1) e += __shfl_xor(e, off, 64);
    float lse = m + logf(e);
    *(float2*)(out + (size_t)wid * 64 + l * 2) = make_float2(v0 - lse, v1 - lse);
}

// ---------------- launch ----------------

extern "C" void kernel_launch(void* const* d_in, const int* in_sizes, int n_in,
                              void* d_out, int out_size, void* d_ws, size_t ws_size,
                              hipStream_t stream) {
    (void)n_in; (void)out_size; (void)ws_size;
    const float* x   = (const float*)d_in[0];
    const int*   row = (const int*)d_in[1];
    const int*   col = (const int*)d_in[2];
    const float* W1  = (const float*)d_in[3];
    const float* b1  = (const float*)d_in[4];
    const float* lng = (const float*)d_in[5];
    const float* lnb = (const float*)d_in[6];
    const float* W2  = (const float*)d_in[7];
    const float* b2  = (const float*)d_in[8];
    float* out = (float*)d_out;

    const int N = in_sizes[0] / 128;
    const int E = in_sizes[1];

    int*   cntAll   = (int*)d_ws;
    int*   startAll = cntAll + N;
    int*   bcur     = startAll + N;            // 512 cursors (pad region to 1024)
    float* nrm      = (float*)(bcur + 1024);
    float* deg1     = nrm + N;                 // zeroed by cast_norm / gather_ln
    float* dinv2    = deg1 + N;
    float* cself    = dinv2 + N;
    int*   cntK     = (int*)(cself + N);
    int*   rowAll   = cntK + N;                // [E]
    int*   colAll   = rowAll + E;              // [E]
    float* simsv    = (float*)(colAll + E);    // [E] sims, then compacted kval
    int*   krow     = (int*)(simsv + E);       // [E] compacted rows
    u32*   fhf      = (u32*)(krow + E);        // [64N] fp16 units; reused as h2hf
    u32*   g2shf    = fhf + (size_t)64 * N;    // [32N]
    float* big      = (float*)(g2shf + (size_t)32 * N);
    float* hs       = big;                     // [128N] layer-1 UNSCALED x@W1
    float* h2       = big + (size_t)128 * N;   // [128N] layer-1 output (persists)
    int2*  ebuf     = (int2*)big;              // [NBKT*BCAP]=21MB CSR scratch
                                               // (dead before fused1 writes hs)

    const int waveBlocks  = (N + 3) / 4;
    const int halfBlocks  = (N + 7) / 8;
    const int flatBlocks  = (E + 127) / 128;   // 128 edges/block (4 waves)
    const int NB          = (N + 255) >> 8;

    // R must be ODD (coprime with the 8-XCD round-robin) — see fused1_k note.
    // Rounding DOWN keeps gemm-block count exact: R*(nGemm-1) < tot guaranteed
    // since R <= tot/nGemm.
    const int nGemm1 = (N + 31) / 32;
    const int tot1   = flatBlocks + nGemm1;
    int R1 = tot1 / nGemm1; if ((R1 & 1) == 0) R1 -= 1; if (R1 < 1) R1 = 1;
    const int nGemm2 = (N + 63) / 64;
    const int tot2   = flatBlocks + nGemm2;
    int R2 = tot2 / nGemm2; if ((R2 & 1) == 0) R2 -= 1; if (R2 < 1) R2 = 1;

    // ---- one-time CSR build ----
    hipMemsetAsync(bcur, 0, NBKT * sizeof(int), stream);
    binfill_k<<<(E + CHUNK - 1) / CHUNK, 256, 0, stream>>>(row, col, bcur, ebuf, E);
    bucket_csr_k<<<NB, 256, 0, stream>>>(ebuf, bcur, startAll, cntAll, rowAll,
                                         colAll, N);

    // ================= layer 1 =================
    cast_norm_k<<<waveBlocks, 256, 0, stream>>>(x, fhf, nrm, deg1, N);
    fused1_k<<<tot1, 256, 0, stream>>>(fhf, x, rowAll, colAll, nrm, simsv, deg1, E,
                                       W1, hs, N, R1, nGemm1);
    edge_c_csr_k<<<waveBlocks, 256, 0, stream>>>(simsv, rowAll, startAll, cntAll,
                                                 deg1, krow, cntK, dinv2, cself, N);
    gather_ln_k<<<halfBlocks, 256, 0, stream>>>(hs, krow, simsv, startAll, cntK,
                                                dinv2, cself, b1, lng, lnb,
                                                h2, fhf, nrm, deg1, N);

    // ================= layer 2 =================
    fused2_k<<<tot2, 256, 0, stream>>>(fhf, h2, rowAll, colAll, nrm, simsv, deg1, E,
                                       W2, g2shf, N, R2, nGemm2);
    edge_c_csr_k<<<waveBlocks, 256, 0, stream>>>(simsv, rowAll, startAll, cntAll,
                                                 deg1, krow, cntK, dinv2, cself, N);
    gather_lsm_hf_k<<<halfBlocks, 256, 0, stream>>>(g2shf, krow, simsv, startAll,
                                                    cntK, dinv2, cself, b2, out, N);
}

// Round 10
// 583.396 us; speedup vs baseline: 1.4947x; 1.0548x over previous
//
#include <hip/hip_runtime.h>
#include <math.h>

#define EPSF 1e-8f
#define LN_EPS 1e-5f
#define BL_MARGIN 0.002f   // > bound on fp16 unit-vector cosine-sim error (~1.5e-3)

#define BKT_SH 8           // 256 cols per bucket
#define NBKT 512           // needs N <= 131072
#define CHUNK 2048         // edges per binfill block
// Per-bucket edges ~ Binomial: mean = 256 cols x (E/N=16) = 4096, sigma ~ 64.
// R5 CRASH POST-MORTEM: BCAP must exceed mean+16sigma (3840 < 4096 faulted).
#define BCAP 5120

// R8/R9 FUSION POST-MORTEM (refuted; this file is the R7 structure restored):
// Fusing GEMM blocks into the edge-dot dispatch lost net perf twice:
//  - R8: gemm blocks at blockIdx%8==0 all landed on ONE XCD (8-XCD round-robin)
//    -> 49-deep serial tail, fused2=408us @ 12.7% occupancy.
//  - R9 (odd R, spread fixed): fused1=189us > 172us sum-of-parts. Cause: the
//    fused kernel's VGPR=60 (vs 36 pure edge) taxes EVERY block -> edge wave
//    occupancy 65%->36% where MLP-per-CU is the binding resource; gemm W/x
//    streams also thrash the L2 serving the random gathers (FETCH 189->230MB).
// Lesson: heterogeneous block fusion with asymmetric register pressure hurts
// the latency-bound role more than the pipe overlap helps.

typedef unsigned int  u32;
typedef unsigned short u16;
typedef _Float16 h2_t __attribute__((ext_vector_type(2)));
typedef _Float16 half8_t __attribute__((ext_vector_type(8)));
typedef float f32x4_t __attribute__((ext_vector_type(4)));

static __device__ inline u32 pack_h2(float a, float b) {
    h2_t h; h.x = (_Float16)a; h.y = (_Float16)b;
    return __builtin_bit_cast(u32, h);
}
static __device__ inline float h2lo(u32 u) {
    return (float)__builtin_bit_cast(h2_t, u).x;
}
static __device__ inline float h2hi(u32 u) {
    return (float)__builtin_bit_cast(h2_t, u).y;
}

// D = A(16x32 f16) * B(32x16 f16) + C, fp32 accumulate.
static __device__ inline f32x4_t mfma16(uint4 a, uint4 b, f32x4_t c) {
    return __builtin_amdgcn_mfma_f32_16x16x32_f16(
        __builtin_bit_cast(half8_t, a), __builtin_bit_cast(half8_t, b), c, 0, 0, 0);
}
static __device__ inline float sel4(f32x4_t a, int m) {
    return m == 0 ? a[0] : m == 1 ? a[1] : m == 2 ? a[2] : a[3];
}

// ---------------- layer-1 prep: norms + UNIT-vector fp16 cast (+deg1 zero) -----
__global__ __launch_bounds__(256) void cast_norm_k(const float* __restrict__ feat,
    u32* __restrict__ fhf, float* __restrict__ nrm, float* __restrict__ deg1, int n) {
    int wid  = (blockIdx.x * 256 + threadIdx.x) >> 6;
    int lane = threadIdx.x & 63;
    if (wid >= n) return;
    float2 v = *(const float2*)(feat + (size_t)wid * 128 + lane * 2);
    float s = v.x * v.x + v.y * v.y;
    #pragma unroll
    for (int off = 32; off; off >>= 1) s += __shfl_xor(s, off, 64);
    float nv = fmaxf(sqrtf(s), EPSF);
    float inv = 1.0f / nv;
    fhf[(size_t)wid * 64 + lane] = pack_h2(v.x * inv, v.y * inv);
    if (lane == 0) { nrm[wid] = nv; deg1[wid] = 0.0f; }
}

// ---------------- one-time CSR build: fixed-capacity bucketed sort ----------------
__global__ __launch_bounds__(256) void binfill_k(const int* __restrict__ row,
    const int* __restrict__ col, int* __restrict__ bcur,
    int2* __restrict__ ebuf, int ecnt) {
    __shared__ int lc[NBKT], ls[NBKT], cur[NBKT], gbase[NBKT];
    __shared__ int2 pairs[CHUNK];
    __shared__ int dstv[CHUNK];
    int t = threadIdx.x;
    int e0 = blockIdx.x * CHUNK;
    int m = min(CHUNK, ecnt - e0);
    lc[t] = 0; lc[t + 256] = 0; cur[t] = 0; cur[t + 256] = 0;
    __syncthreads();
    int myc[CHUNK / 256], myr[CHUNK / 256];
    #pragma unroll
    for (int i = 0; i < CHUNK / 256; ++i) {
        int idx = t + i * 256;
        if (idx < m) {
            myc[i] = col[e0 + idx];
            myr[i] = row[e0 + idx];
            atomicAdd(&lc[myc[i] >> BKT_SH], 1);
        }
    }
    __syncthreads();
    int v0 = lc[t], v1 = lc[t + 256];
    ls[t] = v0; ls[t + 256] = v1; __syncthreads();
    for (int off = 1; off < 256; off <<= 1) {
        int a0 = (t >= off) ? ls[t - off] : 0;
        int a1 = (t >= off) ? ls[256 + t - off] : 0;
        __syncthreads();
        ls[t] += a0; ls[t + 256] += a1;
        __syncthreads();
    }
    int h0 = ls[255];
    int e0x = ls[t] - v0;
    int e1x = ls[t + 256] - v1 + h0;
    __syncthreads();
    ls[t] = e0x; ls[t + 256] = e1x;
    if (v0) gbase[t] = atomicAdd(&bcur[t], v0);
    if (v1) gbase[t + 256] = atomicAdd(&bcur[t + 256], v1);
    __syncthreads();
    #pragma unroll
    for (int i = 0; i < CHUNK / 256; ++i) {
        int idx = t + i * 256;
        if (idx < m) {
            int b = myc[i] >> BKT_SH;
            int s = ls[b] + atomicAdd(&cur[b], 1);
            pairs[s] = make_int2(myc[i], myr[i]);
            int pos = gbase[b] + (s - ls[b]);
            dstv[s]  = (pos < BCAP) ? (b * BCAP + pos) : -1;
        }
    }
    __syncthreads();
    for (int s = t; s < m; s += 256) {
        int d = dstv[s];
        if (d >= 0) ebuf[d] = pairs[s];
    }
}

__global__ __launch_bounds__(256) void bucket_csr_k(const int2* __restrict__ ebuf,
    const int* __restrict__ bcur, int* __restrict__ startAll,
    int* __restrict__ cntAll, int* __restrict__ rowAll, int* __restrict__ colAll,
    int n) {
    __shared__ int sc[NBKT];
    __shared__ int cnt[256], lst[256], cur[256];
    __shared__ int rowbuf[BCAP];
    int b = blockIdx.x, t = threadIdx.x;
    int c0 = b << BKT_SH;
    int s0v = min(bcur[t], BCAP), s1v = min(bcur[t + 256], BCAP);
    sc[t] = s0v; sc[t + 256] = s1v; __syncthreads();
    for (int off = 1; off < 256; off <<= 1) {
        int a0 = (t >= off) ? sc[t - off] : 0;
        int a1 = (t >= off) ? sc[256 + t - off] : 0;
        __syncthreads();
        sc[t] += a0; sc[t + 256] += a1;
        __syncthreads();
    }
    int m  = min(bcur[b], BCAP);
    int g0 = ((b >= 256) ? sc[255] : 0) + sc[b] - m;
    size_t ebase = (size_t)b * BCAP;
    cnt[t] = 0; cur[t] = 0;
    __syncthreads();
    for (int i = t; i < m; i += 256)
        atomicAdd(&cnt[ebuf[ebase + i].x - c0], 1);
    __syncthreads();
    int v = cnt[t];
    lst[t] = v; __syncthreads();
    for (int off = 1; off < 256; off <<= 1) {
        int a = (t >= off) ? lst[t - off] : 0;
        __syncthreads();
        lst[t] += a;
        __syncthreads();
    }
    int ex = lst[t] - v;
    __syncthreads();
    lst[t] = ex;
    __syncthreads();
    int c = c0 + t;
    if (c < n) { startAll[c] = g0 + lst[t]; cntAll[c] = cnt[t]; }
    for (int i = t; i < m; i += 256) {
        int2 p = ebuf[ebase + i];
        int ci = p.x - c0;
        int pos = lst[ci] + atomicAdd(&cur[ci], 1);
        rowbuf[pos] = p.y;
    }
    __syncthreads();
    for (int i = t; i < m; i += 256)
        rowAll[g0 + i] = rowbuf[i];
    __syncthreads();
    {
        int base = lst[t], cn = cnt[t], cc = c0 + t;
        for (int k2 = 0; k2 < cn; ++k2) rowbuf[base + k2] = cc;
    }
    __syncthreads();
    for (int i = t; i < m; i += 256)
        colAll[g0 + i] = rowbuf[i];
}

// ---------------- edge phase A: flat edge-parallel MFMA dots ----------------
// R1-R3 post-mortem: pinned at ~91us across 3 structural variants; per-CU
// outstanding-miss x L2/L3-latency floor for 1.6M x 256B random gathers
// (A-side is L1-hot via col-sorting; row-partitioning would just swap sides).
// Keep this kernel LEAN (VGPR 36) — R9 showed fattening it to 60 VGPR costs
// ~30% of its occupancy and more than any fused work gains.
__global__ __launch_bounds__(256) void edge_dot_flat_k(const u32* __restrict__ fhf,
    const float* __restrict__ feat32, const int* __restrict__ rowAll,
    const int* __restrict__ colAll, const float* __restrict__ nrm,
    float* __restrict__ sims, float* __restrict__ deg1, int ecnt) {
    int wv   = (blockIdx.x * 256 + threadIdx.x) >> 6;
    int lane = threadIdx.x & 63;
    int e0 = wv * 32;
    if (e0 >= ecnt) return;
    int lr = lane & 15, kq = lane >> 4;
    bool diag = (kq == (lr >> 2));
    int m3 = lane & 3;
    int em1 = ecnt - 1;

    int e1 = e0 + lr, e2 = e0 + 16 + lr;
    int e1c = min(e1, em1), e2c = min(e2, em1);
    int r1 = rowAll[e1c], c1 = colAll[e1c];
    int r2 = rowAll[e2c], c2 = colAll[e2c];
    const u32* pa1 = fhf + (size_t)c1 * 64 + kq * 4;
    const u32* pb1 = fhf + (size_t)r1 * 64 + kq * 4;
    const u32* pa2 = fhf + (size_t)c2 * 64 + kq * 4;
    const u32* pb2 = fhf + (size_t)r2 * 64 + kq * 4;
    uint4 a10 = *(const uint4*)(pa1);
    uint4 a11 = *(const uint4*)(pa1 + 16);
    uint4 a12 = *(const uint4*)(pa1 + 32);
    uint4 a13 = *(const uint4*)(pa1 + 48);
    uint4 b10 = *(const uint4*)(pb1);
    uint4 b11 = *(const uint4*)(pb1 + 16);
    uint4 b12 = *(const uint4*)(pb1 + 32);
    uint4 b13 = *(const uint4*)(pb1 + 48);
    uint4 a20 = *(const uint4*)(pa2);
    uint4 a21 = *(const uint4*)(pa2 + 16);
    uint4 a22 = *(const uint4*)(pa2 + 32);
    uint4 a23 = *(const uint4*)(pa2 + 48);
    uint4 b20 = *(const uint4*)(pb2);
    uint4 b21 = *(const uint4*)(pb2 + 16);
    uint4 b22 = *(const uint4*)(pb2 + 32);
    uint4 b23 = *(const uint4*)(pb2 + 48);

    f32x4_t acc1 = {0.f, 0.f, 0.f, 0.f};
    acc1 = mfma16(a10, b10, acc1);
    acc1 = mfma16(a11, b11, acc1);
    acc1 = mfma16(a12, b12, acc1);
    acc1 = mfma16(a13, b13, acc1);
    f32x4_t acc2 = {0.f, 0.f, 0.f, 0.f};
    acc2 = mfma16(a20, b20, acc2);
    acc2 = mfma16(a21, b21, acc2);
    acc2 = mfma16(a22, b22, acc2);
    acc2 = mfma16(a23, b23, acc2);

    float p1 = sel4(acc1, m3);
    float p2 = sel4(acc2, m3);
    bool act1 = diag && (e1 < ecnt);
    bool act2 = diag && (e2 < ecnt);

    // rare fp32 recheck for borderline sims (cooperative, wave-wide)
    unsigned long long bl = __ballot(act1 && fabsf(p1 - 0.1f) < BL_MARGIN);
    while (bl) {
        int src = __ffsll((unsigned long long)bl) - 1; bl &= bl - 1ull;
        int rt = __shfl(r1, src, 64);
        int ct = __shfl(c1, src, 64);
        float2 xa = *(const float2*)(feat32 + (size_t)rt * 128 + lane * 2);
        float2 xb = *(const float2*)(feat32 + (size_t)ct * 128 + lane * 2);
        float s2 = xa.x * xb.x + xa.y * xb.y;
        #pragma unroll
        for (int off = 32; off; off >>= 1) s2 += __shfl_xor(s2, off, 64);
        float pf = s2 / (nrm[rt] * nrm[ct]);
        if (lane == src) p1 = pf;
    }
    unsigned long long bl2 = __ballot(act2 && fabsf(p2 - 0.1f) < BL_MARGIN);
    while (bl2) {
        int src = __ffsll((unsigned long long)bl2) - 1; bl2 &= bl2 - 1ull;
        int rt = __shfl(r2, src, 64);
        int ct = __shfl(c2, src, 64);
        float2 xa = *(const float2*)(feat32 + (size_t)rt * 128 + lane * 2);
        float2 xb = *(const float2*)(feat32 + (size_t)ct * 128 + lane * 2);
        float s2 = xa.x * xb.x + xa.y * xb.y;
        #pragma unroll
        for (int off = 32; off; off >>= 1) s2 += __shfl_xor(s2, off, 64);
        float pf = s2 / (nrm[rt] * nrm[ct]);
        if (lane == src) p2 = pf;
    }
    if (act1) {
        float kv = (p1 >= 0.1f) ? p1 : 0.0f;
        sims[e1] = kv;
        if (kv > 0.0f) atomicAdd(&deg1[r1], kv);
    }
    if (act2) {
        float kv = (p2 >= 0.1f) ? p2 : 0.0f;
        sims[e2] = kv;
        if (kv > 0.0f) atomicAdd(&deg1[r2], kv);
    }
}

// ---------------- edge phase B: vals + in-wave deg2 + compaction ----------------
__global__ __launch_bounds__(256) void edge_c_csr_k(const float* __restrict__ sims,
    const int* __restrict__ rowAll, const int* __restrict__ startAll,
    const int* __restrict__ cntAll, const float* __restrict__ deg1,
    int2* __restrict__ kv, int* __restrict__ cntK, float* __restrict__ dinv2,
    float* __restrict__ cself, int n) {
    int wid  = (blockIdx.x * 256 + threadIdx.x) >> 6;
    int lane = threadIdx.x & 63;
    if (wid >= n) return;
    int s0 = startAll[wid], cnt = cntAll[wid];
    float degc = deg1[wid];
    float d1c = (degc > 0.0f) ? 1.0f / sqrtf(degc) : 0.0f;
    float vsum = 0.0f; int kc = 0;
    for (int jj = 0; jj < cnt; jj += 64) {
        int j = jj + lane;
        bool keep = false; int r = 0; float v = 0.0f;
        if (j < cnt) {
            float s = sims[s0 + j];
            if (s > 0.0f) {
                r = rowAll[s0 + j];
                float dr = 1.0f / sqrtf(deg1[r]);     // deg1[r] >= s >= 0.1
                v = expf(dr * s * d1c);
                keep = true;
            }
        }
        unsigned long long m = __ballot(keep ? 1 : 0);
        if (keep) {
            int pre = __popcll(m & ((1ull << lane) - 1ull));
            int2 pk; pk.x = r; pk.y = __float_as_int(v);
            kv[s0 + kc + pre] = pk;
            vsum += v;
        }
        kc += __popcll(m);
    }
    #pragma unroll
    for (int off = 32; off; off >>= 1) vsum += __shfl_xor(vsum, off, 64);
    if (lane == 0) {
        float ws_ = expf(1.0f / ((float)kc + 1.0f));   // self-loop weight
        float dg = ws_ + vsum;                         // always > 0
        float di = 1.0f / sqrtf(dg);
        dinv2[wid] = di;
        cself[wid] = di * ws_;      // self term uses dinv2-scaled h, so one di here
        cntK[wid]  = kc;
    }
}

// ---------------- GEMMs (K=128), register-tiled ----------
// R6 POST-MORTEM: full-W1 LDS (64KB) cut occupancy to 2 blocks/CU ->
// 93.5us regression. R7 fix: K-SPLIT double phase — W1 half-K slice
// [64][128] = 32KB LDS, acc persists across 2 phases; x read once per thread,
// ~5 blocks/CU. fp32 math mandatory: h2 feeds layer-2 keep/drop thresholds.

__global__ __launch_bounds__(256) void gemm128_k(const float* __restrict__ A,
    const float* __restrict__ W, const float* __restrict__ scale,
    float* __restrict__ out, int n) {
    __shared__ float Ws[64 * 128];            // half-K slice, 32KB
    const int TPN = 32;
    int group = threadIdx.x / TPN;            // 8 groups -> 32 nodes/block
    int tin   = threadIdx.x % TPN;
    int nid   = (blockIdx.x * 8 + group) * 4;
    int dbase = tin * 4;
    int nm1 = n - 1;
    const float4* a0 = (const float4*)(A + (size_t)min(nid,     nm1) * 128);
    const float4* a1 = (const float4*)(A + (size_t)min(nid + 1, nm1) * 128);
    const float4* a2 = (const float4*)(A + (size_t)min(nid + 2, nm1) * 128);
    const float4* a3 = (const float4*)(A + (size_t)min(nid + 3, nm1) * 128);
    float4 acc0 = {0,0,0,0}, acc1 = {0,0,0,0}, acc2 = {0,0,0,0}, acc3 = {0,0,0,0};
    // NOTE: no early return — all threads must hit the phase barriers.
    for (int p = 0; p < 2; ++p) {
        if (p) __syncthreads();               // prev phase's Ws reads complete
        for (int i = threadIdx.x; i < 64 * 128 / 4; i += 256)
            ((float4*)Ws)[i] = ((const float4*)W)[p * (64 * 128 / 4) + i];
        __syncthreads();
        #pragma unroll 2
        for (int k4 = 0; k4 < 16; ++k4) {
            const float* wr = Ws + (k4 * 4) * 128 + dbase;
            float4 w0 = *(const float4*)(wr);
            float4 w1 = *(const float4*)(wr + 128);
            float4 w2 = *(const float4*)(wr + 256);
            float4 w3 = *(const float4*)(wr + 384);
            int ka = p * 16 + k4;
            float4 v0 = a0[ka], v1 = a1[ka], v2 = a2[ka], v3 = a3[ka];
            acc0.x += v0.x*w0.x + v0.y*w1.x + v0.z*w2.x + v0.w*w3.x;
            acc0.y += v0.x*w0.y + v0.y*w1.y + v0.z*w2.y + v0.w*w3.y;
            acc0.z += v0.x*w0.z + v0.y*w1.z + v0.z*w2.z + v0.w*w3.z;
            acc0.w += v0.x*w0.w + v0.y*w1.w + v0.z*w2.w + v0.w*w3.w;
            acc1.x += v1.x*w0.x + v1.y*w1.x + v1.z*w2.x + v1.w*w3.x;
            acc1.y += v1.x*w0.y + v1.y*w1.y + v1.z*w2.y + v1.w*w3.y;
            acc1.z += v1.x*w0.z + v1.y*w1.z + v1.z*w2.z + v1.w*w3.z;
            acc1.w += v1.x*w0.w + v1.y*w1.w + v1.z*w2.w + v1.w*w3.w;
            acc2.x += v2.x*w0.x + v2.y*w1.x + v2.z*w2.x + v2.w*w3.x;
            acc2.y += v2.x*w0.y + v2.y*w1.y + v2.z*w2.y + v2.w*w3.y;
            acc2.z += v2.x*w0.z + v2.y*w1.z + v2.z*w2.z + v2.w*w3.z;
            acc2.w += v2.x*w0.w + v2.y*w1.w + v2.z*w2.w + v2.w*w3.w;
            acc3.x += v3.x*w0.x + v3.y*w1.x + v3.z*w2.x + v3.w*w3.x;
            acc3.y += v3.x*w0.y + v3.y*w1.y + v3.z*w2.y + v3.w*w3.y;
            acc3.z += v3.x*w0.z + v3.y*w1.z + v3.z*w2.z + v3.w*w3.z;
            acc3.w += v3.x*w0.w + v3.y*w1.w + v3.z*w2.w + v3.w*w3.w;
        }
    }
    float4 accs[4] = {acc0, acc1, acc2, acc3};
    #pragma unroll
    for (int i = 0; i < 4; ++i) {
        if (nid + i < n) {
            float sc = scale[nid + i];
            float4 r; r.x = accs[i].x * sc; r.y = accs[i].y * sc;
            r.z = accs[i].z * sc; r.w = accs[i].w * sc;
            *(float4*)(out + (size_t)(nid + i) * 128 + dbase) = r;
        }
    }
}

// full-W2 tile (32KB) single pass — never occupancy-limited (not in top-5).
__global__ __launch_bounds__(256) void gemm64_hf_k(const float* __restrict__ A,
    const float* __restrict__ W, const float* __restrict__ scale,
    u32* __restrict__ outhf, int n) {
    __shared__ float Ws[128 * 64];
    for (int i = threadIdx.x; i < 128 * 64 / 4; i += 256)
        ((float4*)Ws)[i] = ((const float4*)W)[i];
    __syncthreads();
    const int TPN = 16;
    int group = threadIdx.x / TPN;            // 16 groups -> 64 nodes/block
    int tin   = threadIdx.x % TPN;
    int nid   = (blockIdx.x * 16 + group) * 4;
    if (nid >= n) return;
    int dbase = tin * 4;
    int nm1 = n - 1;
    const float4* a0 = (const float4*)(A + (size_t)min(nid,     nm1) * 128);
    const float4* a1 = (const float4*)(A + (size_t)min(nid + 1, nm1) * 128);
    const float4* a2 = (const float4*)(A + (size_t)min(nid + 2, nm1) * 128);
    const float4* a3 = (const float4*)(A + (size_t)min(nid + 3, nm1) * 128);
    float4 acc0 = {0,0,0,0}, acc1 = {0,0,0,0}, acc2 = {0,0,0,0}, acc3 = {0,0,0,0};
    #pragma unroll 2
    for (int k4 = 0; k4 < 32; ++k4) {
        const float* wr = Ws + (k4 * 4) * 64 + dbase;
        float4 w0 = *(const float4*)(wr);
        float4 w1 = *(const float4*)(wr + 64);
        float4 w2 = *(const float4*)(wr + 128);
        float4 w3 = *(const float4*)(wr + 192);
        float4 v0 = a0[k4], v1 = a1[k4], v2 = a2[k4], v3 = a3[k4];
        acc0.x += v0.x*w0.x + v0.y*w1.x + v0.z*w2.x + v0.w*w3.x;
        acc0.y += v0.x*w0.y + v0.y*w1.y + v0.z*w2.y + v0.w*w3.y;
        acc0.z += v0.x*w0.z + v0.y*w1.z + v0.z*w2.z + v0.w*w3.z;
        acc0.w += v0.x*w0.w + v0.y*w1.w + v0.z*w2.w + v0.w*w3.w;
        acc1.x += v1.x*w0.x + v1.y*w1.x + v1.z*w2.x + v1.w*w3.x;
        acc1.y += v1.x*w0.y + v1.y*w1.y + v1.z*w2.y + v1.w*w3.y;
        acc1.z += v1.x*w0.z + v1.y*w1.z + v1.z*w2.z + v1.w*w3.z;
        acc1.w += v1.x*w0.w + v1.y*w1.w + v1.z*w2.w + v1.w*w3.w;
        acc2.x += v2.x*w0.x + v2.y*w1.x + v2.z*w2.x + v2.w*w3.x;
        acc2.y += v2.x*w0.y + v2.y*w1.y + v2.z*w2.y + v2.w*w3.y;
        acc2.z += v2.x*w0.z + v2.y*w1.z + v2.z*w2.z + v2.w*w3.z;
        acc2.w += v2.x*w0.w + v2.y*w1.w + v2.z*w2.w + v2.w*w3.w;
        acc3.x += v3.x*w0.x + v3.y*w1.x + v3.z*w2.x + v3.w*w3.x;
        acc3.y += v3.x*w0.y + v3.y*w1.y + v3.z*w2.y + v3.w*w3.y;
        acc3.z += v3.x*w0.z + v3.y*w1.z + v3.z*w2.z + v3.w*w3.z;
        acc3.w += v3.x*w0.w + v3.y*w1.w + v3.z*w2.w + v3.w*w3.w;
    }
    float4 accs[4] = {acc0, acc1, acc2, acc3};
    #pragma unroll
    for (int i = 0; i < 4; ++i) {
        if (nid + i < n) {
            float sc = scale[nid + i];
            u32 o0 = pack_h2(accs[i].x * sc, accs[i].y * sc);
            u32 o1 = pack_h2(accs[i].z * sc, accs[i].w * sc);
            *(uint2*)(outhf + (size_t)(nid + i) * 32 + tin * 2)
                = make_uint2(o0, o1);
        }
    }
}

// ---------------- fused gather epilogues (half-wave per node) ----------------
// R4: masked 8-wide batches (clamped index, zeroed weight) replace the dynamic
// remainder loop -> all gathers of a batch in flight, no serial dependent chain.

__global__ __launch_bounds__(256) void gather_ln_k(const float* __restrict__ hs,
    const int2* __restrict__ kv, const int* __restrict__ startAll,
    const int* __restrict__ cntK, const float* __restrict__ dinv2,
    const float* __restrict__ cself, const float* __restrict__ bias,
    const float* __restrict__ g, const float* __restrict__ bln,
    float* __restrict__ outbuf, u32* __restrict__ outhf,
    float* __restrict__ nrm, float* __restrict__ deg1, int n) {
    int wid = (blockIdx.x * 256 + threadIdx.x) >> 5;
    int l   = threadIdx.x & 31;
    if (wid >= n) return;
    int s0 = startAll[wid], k = cntK[wid];
    if (l == 0) deg1[wid] = 0.0f;               // pre-zero for layer-2 edge_dot
    float4 acc = {0,0,0,0};
    int km1 = s0 + k - 1;
    for (int j0 = 0; j0 < k; j0 += 8) {
        int2 p[8];
        #pragma unroll
        for (int i = 0; i < 8; ++i) p[i] = kv[min(s0 + j0 + i, km1)];
        float4 h[8];
        #pragma unroll
        for (int i = 0; i < 8; ++i)
            h[i] = *(const float4*)(hs + (size_t)p[i].x * 128 + l * 4);
        #pragma unroll
        for (int i = 0; i < 8; ++i) {
            float v = (j0 + i < k) ? __int_as_float(p[i].y) : 0.0f;
            acc.x += v * h[i].x; acc.y += v * h[i].y;
            acc.z += v * h[i].z; acc.w += v * h[i].w;
        }
    }
    float di = dinv2[wid], cs = cself[wid];
    float4 hsv = *(const float4*)(hs + (size_t)wid * 128 + l * 4);
    float4 vb  = *(const float4*)(bias + l * 4);
    float x0 = di*acc.x + cs*hsv.x + vb.x;
    float x1 = di*acc.y + cs*hsv.y + vb.y;
    float x2 = di*acc.z + cs*hsv.z + vb.z;
    float x3 = di*acc.w + cs*hsv.w + vb.w;
    float s = x0 + x1 + x2 + x3;
    #pragma unroll
    for (int off = 16; off; off >>= 1) s += __shfl_xor(s, off, 64);
    float mu = s * (1.0f / 128.0f);
    float d0 = x0 - mu, d1 = x1 - mu, d2 = x2 - mu, d3 = x3 - mu;
    float vv = d0*d0 + d1*d1 + d2*d2 + d3*d3;
    #pragma unroll
    for (int off = 16; off; off >>= 1) vv += __shfl_xor(vv, off, 64);
    float rstd = 1.0f / sqrtf(vv * (1.0f / 128.0f) + LN_EPS);
    float4 vg  = *(const float4*)(g + l * 4);
    float4 vbl = *(const float4*)(bln + l * 4);
    float y0 = fmaxf(d0 * rstd * vg.x + vbl.x, 0.0f);
    float y1 = fmaxf(d1 * rstd * vg.y + vbl.y, 0.0f);
    float y2 = fmaxf(d2 * rstd * vg.z + vbl.z, 0.0f);
    float y3 = fmaxf(d3 * rstd * vg.w + vbl.w, 0.0f);
    float4 yo; yo.x = y0; yo.y = y1; yo.z = y2; yo.w = y3;
    *(float4*)(outbuf + (size_t)wid * 128 + l * 4) = yo;
    float ns = y0*y0 + y1*y1 + y2*y2 + y3*y3;
    #pragma unroll
    for (int off = 16; off; off >>= 1) ns += __shfl_xor(ns, off, 64);
    float nv = fmaxf(sqrtf(ns), EPSF);
    float inv = 1.0f / nv;
    uint2 oh; oh.x = pack_h2(y0 * inv, y1 * inv); oh.y = pack_h2(y2 * inv, y3 * inv);
    *(uint2*)(outhf + (size_t)wid * 64 + l * 2) = oh;
    if (l == 0) nrm[wid] = nv;
}

__global__ __launch_bounds__(256) void gather_lsm_hf_k(const u32* __restrict__ g2s,
    const int2* __restrict__ kv, const int* __restrict__ startAll,
    const int* __restrict__ cntK, const float* __restrict__ dinv2,
    const float* __restrict__ cself, const float* __restrict__ b2,
    float* __restrict__ out, int n) {
    int wid = (blockIdx.x * 256 + threadIdx.x) >> 5;
    int l   = threadIdx.x & 31;
    if (wid >= n) return;
    int s0 = startAll[wid], k = cntK[wid];
    float acc0 = 0.f, acc1 = 0.f;
    int km1 = s0 + k - 1;
    for (int j0 = 0; j0 < k; j0 += 8) {
        int2 p[8];
        #pragma unroll
        for (int i = 0; i < 8; ++i) p[i] = kv[min(s0 + j0 + i, km1)];
        u32 gv[8];
        #pragma unroll
        for (int i = 0; i < 8; ++i) gv[i] = g2s[(size_t)p[i].x * 32 + l];
        #pragma unroll
        for (int i = 0; i < 8; ++i) {
            float v = (j0 + i < k) ? __int_as_float(p[i].y) : 0.0f;
            acc0 += v * h2lo(gv[i]); acc1 += v * h2hi(gv[i]);
        }
    }
    float di = dinv2[wid], cs = cself[wid];
    u32 gsu = g2s[(size_t)wid * 32 + l];
    float2 vb = *(const float2*)(b2 + l * 2);
    float v0 = di * acc0 + cs * h2lo(gsu) + vb.x;
    float v1 = di * acc1 + cs * h2hi(gsu) + vb.y;
    float m = fmaxf(v0, v1);
    #pragma unroll
    for (int off = 16; off; off >>= 1) m = fmaxf(m, __shfl_xor(m, off, 64));
    float e = expf(v0 - m) + expf(v1 - m);
    #pragma unroll
    for (int off = 16; off; off >>= 1) e += __shfl_xor(e, off, 64);
    float lse = m + logf(e);
    *(float2*)(out + (size_t)wid * 64 + l * 2) = make_float2(v0 - lse, v1 - lse);
}

// ---------------- launch ----------------

extern "C" void kernel_launch(void* const* d_in, const int* in_sizes, int n_in,
                              void* d_out, int out_size, void* d_ws, size_t ws_size,
                              hipStream_t stream) {
    (void)n_in; (void)out_size; (void)ws_size;
    const float* x   = (const float*)d_in[0];
    const int*   row = (const int*)d_in[1];
    const int*   col = (const int*)d_in[2];
    const float* W1  = (const float*)d_in[3];
    const float* b1  = (const float*)d_in[4];
    const float* lng = (const float*)d_in[5];
    const float* lnb = (const float*)d_in[6];
    const float* W2  = (const float*)d_in[7];
    const float* b2  = (const float*)d_in[8];
    float* out = (float*)d_out;

    const int N = in_sizes[0] / 128;
    const int E = in_sizes[1];

    int*   cntAll   = (int*)d_ws;
    int*   startAll = cntAll + N;
    int*   bcur     = startAll + N;            // 512 cursors (pad region to 1024)
    float* nrm      = (float*)(bcur + 1024);
    float* deg1     = nrm + N;                 // zeroed by cast_norm / gather_ln
    float* dinv2    = deg1 + N;
    float* cself    = dinv2 + N;
    int*   cntK     = (int*)(cself + N);       // kept counts (written by edge_c)
    int*   rowAll   = cntK + N;                // [E]
    int*   colAll   = rowAll + E;              // [E] col id per CSR position
    int2*  kvp      = (int2*)(colAll + E);     // [E] packed (row, val)
    u32*   fhf      = (u32*)(kvp + E);         // [64N] u32 = [128N] fp16; reused as h2hf
    u32*   g2shf    = fhf + (size_t)64 * N;    // [32N] u32 = [64N] fp16
    float* big      = (float*)(g2shf + (size_t)32 * N);
    float* sims     = big;                     // [E]  (dead before hs is written)
    float* hs       = big;                     // [128N] layer-1 scaled h
    float* h2       = big + (size_t)128 * N;   // [128N] layer-1 output (persists)
    int2*  ebuf     = (int2*)big;              // [NBKT*BCAP]=21MB CSR scratch
                                               // (dead before sims is written)

    const int waveBlocks  = (N + 3) / 4;       // 1 wave/node
    const int halfBlocks  = (N + 7) / 8;       // half-wave/node
    const int flatBlocks  = (E + 127) / 128;   // 32 edges/wave
    const int NB          = (N + 255) >> 8;    // buckets actually populated

    // ---- one-time CSR build (3 nodes: memset + binfill + bucket_csr) ----
    hipMemsetAsync(bcur, 0, NBKT * sizeof(int), stream);
    binfill_k<<<(E + CHUNK - 1) / CHUNK, 256, 0, stream>>>(row, col, bcur, ebuf, E);
    bucket_csr_k<<<NB, 256, 0, stream>>>(ebuf, bcur, startAll, cntAll, rowAll,
                                         colAll, N);

    // ================= layer 1 =================
    cast_norm_k<<<waveBlocks, 256, 0, stream>>>(x, fhf, nrm, deg1, N);
    edge_dot_flat_k<<<flatBlocks, 256, 0, stream>>>(fhf, x, rowAll, colAll, nrm,
                                                    sims, deg1, E);
    edge_c_csr_k<<<waveBlocks, 256, 0, stream>>>(sims, rowAll, startAll, cntAll, deg1,
                                                 kvp, cntK, dinv2, cself, N);
    gemm128_k<<<(N + 31) / 32, 256, 0, stream>>>(x, W1, dinv2, hs, N);
    gather_ln_k<<<halfBlocks, 256, 0, stream>>>(hs, kvp, startAll, cntK, dinv2, cself,
                                                b1, lng, lnb, h2, fhf, nrm, deg1, N);

    // ================= layer 2 =================
    edge_dot_flat_k<<<flatBlocks, 256, 0, stream>>>(fhf, h2, rowAll, colAll, nrm,
                                                    sims, deg1, E);
    edge_c_csr_k<<<waveBlocks, 256, 0, stream>>>(sims, rowAll, startAll, cntAll, deg1,
                                                 kvp, cntK, dinv2, cself, N);
    gemm64_hf_k<<<(N + 63) / 64, 256, 0, stream>>>(h2, W2, dinv2, g2shf, N);
    gather_lsm_hf_k<<<halfBlocks, 256, 0, stream>>>(g2shf, kvp, startAll, cntK, dinv2,
                                                    cself, b2, out, N);
}